// Round 13
// baseline (135.268 us; speedup 1.0000x reference)
//
#include <hip/hip_runtime.h>
#include <hip/hip_bf16.h>
#include <math.h>

#define D_MODEL 512
#define D_FF    2048
#define NEXP    8
#define NXCD    8

using bf16x8 = __attribute__((ext_vector_type(8))) short;
using f32x4  = __attribute__((ext_vector_type(4))) float;

__device__ inline unsigned short f2bf(float x) {
    __hip_bfloat16 h = __float2bfloat16(x);
    unsigned short u; __builtin_memcpy(&u, &h, 2); return u;
}
__device__ inline unsigned pk(float a, float b) {
    return (unsigned)f2bf(a) | ((unsigned)f2bf(b) << 16);
}
// A&S 7.1.26 rational erf, |err| <= 1.5e-7 (invisible at bf16 output)
__device__ inline float erf_fast(float x) {
    float ax = fabsf(x);
    float t  = 1.f / fmaf(0.3275911f, ax, 1.f);
    float p  = t * fmaf(t, fmaf(t, fmaf(t, fmaf(t, 1.061405429f, -1.453152027f),
                                        1.421413741f), -0.284496736f), 0.254829592f);
    float r  = 1.f - p * __expf(-ax * ax);
    return copysignf(r, x);
}
__device__ inline float gelu_exact(float v) {
    return 0.5f * v * (1.f + erf_fast(v * 0.70710678118654752f));
}
__device__ inline void gload_lds16(const void* g, void* l) {
    __builtin_amdgcn_global_load_lds(
        (const __attribute__((address_space(1))) unsigned int*)g,
        (__attribute__((address_space(3))) unsigned int*)l, 16, 0, 0);
}

// ---------------- Gating: one wave per token, NO atomics ----------------
__global__ __launch_bounds__(256) void gate_kernel(
    const float* __restrict__ x, const float* __restrict__ Wg,
    const float* __restrict__ bg,
    int2* __restrict__ tk_e, float2* __restrict__ tk_s,
    unsigned short* __restrict__ Xb, int T)
{
    int lane = threadIdx.x & 63;
    int w    = threadIdx.x >> 6;
    int t    = blockIdx.x * 4 + w;
    if (t >= T) return;

    const float* xr = x + (size_t)t * D_MODEL;
    unsigned short* xbr = Xb ? (Xb + (size_t)t * D_MODEL) : nullptr;
    float lg[NEXP];
#pragma unroll
    for (int e = 0; e < NEXP; e++) lg[e] = 0.f;

#pragma unroll
    for (int it = 0; it < D_MODEL / 64; it++) {
        int d = lane + 64 * it;
        float xv = xr[d];
        if (xbr) xbr[d] = f2bf(xv);
        const float* wr = Wg + (size_t)d * NEXP;
#pragma unroll
        for (int e = 0; e < NEXP; e++) lg[e] += xv * wr[e];
    }
#pragma unroll
    for (int off = 32; off > 0; off >>= 1) {
#pragma unroll
        for (int e = 0; e < NEXP; e++) lg[e] += __shfl_xor(lg[e], off, 64);
    }

    if (lane == 0) {
#pragma unroll
        for (int e = 0; e < NEXP; e++) lg[e] += bg[e];
        int e0 = 0;
#pragma unroll
        for (int e = 1; e < NEXP; e++) if (lg[e] > lg[e0]) e0 = e;
        int e1 = (e0 == 0) ? 1 : 0;
#pragma unroll
        for (int e = 0; e < NEXP; e++) if (e != e0 && lg[e] > lg[e1]) e1 = e;
        float s0 = 1.f / (1.f + expf(lg[e1] - lg[e0]));
        tk_e[t] = make_int2(e0, e1);
        tk_s[t] = make_float2(s0, 1.f - s0);
    }
}

// ---------------- Routing: wave-aggregated list append + slot record ----------------
__global__ __launch_bounds__(256) void route_kernel(
    const int2* __restrict__ tk_e, const float2* __restrict__ tk_s,
    int* __restrict__ counts, int* __restrict__ ltok, float* __restrict__ lsc,
    int2* __restrict__ tk_pos, int T)
{
    int t    = blockIdx.x * 256 + threadIdx.x;
    int lane = threadIdx.x & 63;
    bool valid = t < T;
    int2   es = valid ? tk_e[t] : make_int2(-1, -1);
    float2 ss = valid ? tk_s[t] : make_float2(0.f, 0.f);
    int ppos[2] = {0, 0};

#pragma unroll
    for (int slot = 0; slot < 2; slot++) {
        int   e = slot ? es.y : es.x;
        float s = slot ? ss.y : ss.x;
#pragma unroll
        for (int ex = 0; ex < NEXP; ex++) {
            unsigned long long m = __ballot(e == ex);
            if (m == 0ull) continue;
            int leader = __ffsll((long long)m) - 1;
            int base = 0;
            if (lane == leader) base = atomicAdd(&counts[ex], __popcll(m));
            base = __shfl(base, leader, 64);
            if (e == ex) {
                int pos = base + __popcll(m & ((1ull << lane) - 1ull));
                ltok[(size_t)ex * T + pos] = t;
                lsc [(size_t)ex * T + pos] = s;
                ppos[slot] = pos | (ex << 16);
            }
        }
    }
    if (valid) tk_pos[t] = make_int2(ppos[0], ppos[1]);
}

__global__ void prefix_kernel(const int* __restrict__ counts, int* __restrict__ offs)
{
    if (threadIdx.x == 0) {
        int acc = 0;
        for (int e = 0; e < NEXP; e++) { offs[e] = acc; acc += counts[e]; }
        offs[NEXP] = acc;
    }
}

// ---------------- Transpose-convert: src[e][R][C] f32 -> dst[e][C][R] bf16 ----------------
__global__ __launch_bounds__(256) void tcvt_kernel(
    const float* __restrict__ src, unsigned short* __restrict__ dst, int R, int C)
{
    __shared__ unsigned short tile[64][72];
    int e  = blockIdx.z;
    int r0 = blockIdx.y * 64, c0 = blockIdx.x * 64;
    const float* s = src + ((size_t)e * R + r0) * C + c0;
    unsigned short* d = dst + ((size_t)e * C + c0) * R + r0;
    int t = threadIdx.x;
#pragma unroll
    for (int i = 0; i < 4; i++) {
        int idx = t + 256 * i;
        int r = idx >> 4, c4 = (idx & 15) * 4;
        float4 v = *(const float4*)(s + (size_t)r * C + c4);
        tile[c4    ][r] = f2bf(v.x);
        tile[c4 + 1][r] = f2bf(v.y);
        tile[c4 + 2][r] = f2bf(v.z);
        tile[c4 + 3][r] = f2bf(v.w);
    }
    __syncthreads();
#pragma unroll
    for (int i = 0; i < 2; i++) {
        int idx = t + 256 * i;
        int c = idx >> 3, q = idx & 7;
        uint4 v = *(const uint4*)(&tile[c][q * 8]);
        *(uint4*)(d + (size_t)c * R + q * 8) = v;
    }
}

// ---------------- GEMM1: H = gelu(Xb @ W1t^T + b1) ----------------
// R12 (unchanged): 128x128, 4 waves, 2 barriers/step, XCD swizzle.
__global__ __launch_bounds__(256, 4) void moe_gemm1(
    const unsigned short* __restrict__ Xb,
    const unsigned short* __restrict__ W1t, const float* __restrict__ b1,
    const int* __restrict__ counts, const int* __restrict__ offs,
    const int* __restrict__ ltok,
    unsigned short* __restrict__ Hg, int T)
{
    int nwg  = gridDim.x;
    int bid  = blockIdx.x;
    int work = (bid % NXCD) * (nwg / NXCD) + bid / NXCD;
    int perexp = nwg / NEXP;
    int e    = work / perexp;
    int rem  = work % perexp;
    int mbase = (rem >> 4) * 128;
    int fb    = (rem & 15) * 128;

    int n = counts[e];
    if (mbase >= n) return;
    int off = offs[e];

    __shared__ __align__(16) unsigned char SB[2][16384];
    __shared__ int toks_s[128];

    int tid = threadIdx.x, lane = tid & 63, w = tid >> 6;
    int wr = w & 1, wc = w >> 1;

    if (tid < 128) {
        int idx = mbase + tid; if (idx > n - 1) idx = n - 1;
        toks_s[tid] = ltok[(size_t)e * T + idx];
    }
    __syncthreads();

    const unsigned short* W1te = W1t + (size_t)e * D_FF * D_MODEL;
    int c = lane & 7, rsub = lane >> 3;

    const char* aptr[4]; const char* bptr[4]; int soff[4];
#pragma unroll
    for (int j = 0; j < 4; j++) {
        int r  = j * 32 + w * 8 + rsub;
        int sc = c ^ (r & 7);
        aptr[j] = (const char*)(Xb + (size_t)toks_s[r] * D_MODEL) + sc * 16;
        bptr[j] = (const char*)(W1te + (size_t)(fb + r) * D_MODEL) + sc * 16;
        soff[j] = (j * 32 + w * 8) * 128;
    }

    f32x4 acc[4][4];
#pragma unroll
    for (int i = 0; i < 4; i++)
#pragma unroll
        for (int j = 0; j < 4; j++) acc[i][j] = (f32x4){0.f, 0.f, 0.f, 0.f};

    for (int kc = 0; kc < D_MODEL; kc += 64) {
#pragma unroll
        for (int j = 0; j < 4; j++) gload_lds16(aptr[j] + kc * 2, SB[0] + soff[j]);
#pragma unroll
        for (int j = 0; j < 4; j++) gload_lds16(bptr[j] + kc * 2, SB[1] + soff[j]);
        __syncthreads();

#pragma unroll
        for (int ks = 0; ks < 2; ks++) {
            bf16x8 av[4], bv[4];
            int kbyte = ks * 64 + ((lane >> 4) * 16);
#pragma unroll
            for (int i = 0; i < 4; i++) {
                int row = wr * 64 + i * 16 + (lane & 15);
                av[i] = *(const bf16x8*)(SB[0] + row * 128 + (kbyte ^ ((row & 7) << 4)));
            }
#pragma unroll
            for (int j = 0; j < 4; j++) {
                int fr = wc * 64 + j * 16 + (lane & 15);
                bv[j] = *(const bf16x8*)(SB[1] + fr * 128 + (kbyte ^ ((fr & 7) << 4)));
            }
#pragma unroll
            for (int i = 0; i < 4; i++)
#pragma unroll
                for (int j = 0; j < 4; j++)
                    acc[i][j] = __builtin_amdgcn_mfma_f32_16x16x32_bf16(av[i], bv[j], acc[i][j], 0, 0, 0);
        }
        __syncthreads();
    }

    // epilogue: bias+GELU -> swizzled LDS (bf16) -> coalesced uint4 stores
    char* Eb = (char*)&SB[0][0];
    const float* b1e = b1 + (size_t)e * D_FF;
#pragma unroll
    for (int j = 0; j < 4; j++) {
        int col = wc * 64 + j * 16 + (lane & 15);
        float b1v = b1e[fb + col];
#pragma unroll
        for (int i = 0; i < 4; i++) {
#pragma unroll
            for (int r = 0; r < 4; r++) {
                int row = wr * 64 + i * 16 + (lane >> 4) * 4 + r;
                float v = gelu_exact(acc[i][j][r] + b1v);
                *(unsigned short*)(Eb + row * 256 + ((col * 2) ^ ((row & 7) << 4))) = f2bf(v);
            }
        }
    }
    __syncthreads();
#pragma unroll
    for (int k = 0; k < 8; k++) {
        int idx = tid + 256 * k;
        int row = idx >> 4, ch = idx & 15;
        if (mbase + row < n) {
            uint4 v = *(const uint4*)(Eb + row * 256 + ((ch * 16) ^ ((row & 7) << 4)));
            *(uint4*)(Hg + (size_t)(off + mbase + row) * D_FF + fb + ch * 8) = v;
        }
    }
}

// ---------------- GEMM2 (atomic-free): Og[kb][slot][d] = s*(H@W2t^T + b2) ----------------
// M-tile 64 (was 128): active blocks 8e x 16mt x 4nb x 2kb = 1024 = 4/CU.
// 4 waves (2M x 2N), per-wave 32x64, acc[2][4]. XCD swizzle kept.
__global__ __launch_bounds__(256, 4) void moe_gemm2_og(
    const unsigned short* __restrict__ Hg,
    const unsigned short* __restrict__ W2t, const float* __restrict__ b2,
    const int* __restrict__ counts, const int* __restrict__ offs,
    const int* __restrict__ ltok, const float* __restrict__ lsc,
    float* __restrict__ Og, int T)
{
    // grid = NEXP * (T/64) * 8 (nb x kb), %8==0
    int nwg  = gridDim.x;
    int bid  = blockIdx.x;
    int work = (bid % NXCD) * (nwg / NXCD) + bid / NXCD;
    int perexp = nwg / NEXP;
    int e    = work / perexp;
    int rem  = work % perexp;
    int mbase = (rem >> 3) * 64;
    int z    = rem & 7;
    int nb   = z & 3, kb = z >> 2;
    int db   = nb * 128;

    int n = counts[e];
    if (mbase >= n) return;
    int off = offs[e];

    __shared__ __align__(16) unsigned char HsB[64 * 128];    // A: 64 t x 64 k (8 KB)
    __shared__ __align__(16) unsigned char WsB[128 * 128];   // B: 128 d x 64 k (16 KB)
    __shared__ float scs_s[64];

    int tid = threadIdx.x, lane = tid & 63, w = tid >> 6;
    int wr = w & 1, wc = w >> 1;

    if (tid < 64) {
        int idx = mbase + tid; if (idx > n - 1) idx = n - 1;
        scs_s[tid] = lsc[(size_t)e * T + idx];
    }
    __syncthreads();

    const unsigned short* W2te = W2t + (size_t)e * D_MODEL * D_FF;
    int c = lane & 7, rsub = lane >> 3;

    const char* aptr[2]; int soffA[2];
#pragma unroll
    for (int j = 0; j < 2; j++) {
        int r = j * 32 + w * 8 + rsub;          // 0..63
        int srow = mbase + r; if (srow > n - 1) srow = n - 1;
        int sc = c ^ (r & 7);
        aptr[j]  = (const char*)(Hg + (size_t)(off + srow) * D_FF) + sc * 16;
        soffA[j] = (j * 32 + w * 8) * 128;
    }
    const char* bptr[4]; int soffB[4];
#pragma unroll
    for (int j = 0; j < 4; j++) {
        int r  = j * 32 + w * 8 + rsub;         // 0..127
        int sc = c ^ (r & 7);
        bptr[j]  = (const char*)(W2te + (size_t)(db + r) * D_FF) + sc * 16;
        soffB[j] = (j * 32 + w * 8) * 128;
    }

    f32x4 acc[2][4];
#pragma unroll
    for (int i = 0; i < 2; i++)
#pragma unroll
        for (int j = 0; j < 4; j++) acc[i][j] = (f32x4){0.f, 0.f, 0.f, 0.f};

    int kbase = kb * 1024;
    for (int kc = 0; kc < 1024; kc += 64) {
        int kabs = kbase + kc;
#pragma unroll
        for (int j = 0; j < 2; j++) gload_lds16(aptr[j] + kabs * 2, HsB + soffA[j]);
#pragma unroll
        for (int j = 0; j < 4; j++) gload_lds16(bptr[j] + kabs * 2, WsB + soffB[j]);
        __syncthreads();

#pragma unroll
        for (int ks = 0; ks < 2; ks++) {
            bf16x8 av[2], bv[4];
            int kbyte = ks * 64 + ((lane >> 4) * 16);
#pragma unroll
            for (int i = 0; i < 2; i++) {
                int row = wr * 32 + i * 16 + (lane & 15);
                av[i] = *(const bf16x8*)(HsB + row * 128 + (kbyte ^ ((row & 7) << 4)));
            }
#pragma unroll
            for (int j = 0; j < 4; j++) {
                int dr = wc * 64 + j * 16 + (lane & 15);
                bv[j] = *(const bf16x8*)(WsB + dr * 128 + (kbyte ^ ((dr & 7) << 4)));
            }
#pragma unroll
            for (int i = 0; i < 2; i++)
#pragma unroll
                for (int j = 0; j < 4; j++)
                    acc[i][j] = __builtin_amdgcn_mfma_f32_16x16x32_bf16(av[i], bv[j], acc[i][j], 0, 0, 0);
        }
        __syncthreads();
    }

    // plain coalesced-granule stores; kb planes disjoint -> no race, no atomics
    float* Ogk = Og + (size_t)kb * (2 * T) * D_MODEL;
#pragma unroll
    for (int j = 0; j < 4; j++) {
        int dg = db + wc * 64 + j * 16 + (lane & 15);
        float b2v = (kb == 0) ? b2[(size_t)e * D_MODEL + dg] : 0.f;
#pragma unroll
        for (int i = 0; i < 2; i++) {
#pragma unroll
            for (int r = 0; r < 4; r++) {
                int rowm = wr * 32 + i * 16 + (lane >> 4) * 4 + r;
                if (mbase + rowm < n) {
                    float s = scs_s[rowm];
                    Ogk[(size_t)(off + mbase + rowm) * D_MODEL + dg] = s * (acc[i][j][r] + b2v);
                }
            }
        }
    }
}

// ---------------- Combine: out[t] = sum of 4 partial rows ----------------
__global__ __launch_bounds__(256) void combine_kernel(
    const float* __restrict__ Og, const int* __restrict__ offs,
    const int2* __restrict__ tk_pos, float* __restrict__ out, int T)
{
    int w = threadIdx.x >> 6, lane = threadIdx.x & 63;
    int t = blockIdx.x * 4 + w;
    if (t >= T) return;
    int2 p = tk_pos[t];
    int sA = offs[p.x >> 16] + (p.x & 0xffff);
    int sB = offs[p.y >> 16] + (p.y & 0xffff);
    size_t S = (size_t)(2 * T) * D_MODEL;
    const float4* r0 = (const float4*)(Og + (size_t)sA * D_MODEL);
    const float4* r1 = (const float4*)(Og + S + (size_t)sA * D_MODEL);
    const float4* r2 = (const float4*)(Og + (size_t)sB * D_MODEL);
    const float4* r3 = (const float4*)(Og + S + (size_t)sB * D_MODEL);
    float4* o = (float4*)(out + (size_t)t * D_MODEL);
#pragma unroll
    for (int i = 0; i < 2; i++) {
        int idx = lane + 64 * i;
        float4 a = r0[idx], b = r1[idx], cc = r2[idx], d = r3[idx];
        o[idx] = make_float4(a.x + b.x + cc.x + d.x, a.y + b.y + cc.y + d.y,
                             a.z + b.z + cc.z + d.z, a.w + b.w + cc.w + d.w);
    }
}

// ---------------- GEMM2 (atomic fallback, small-ws path) ----------------
__global__ __launch_bounds__(256, 4) void moe_gemm2(
    const unsigned short* __restrict__ Hg,
    const unsigned short* __restrict__ W2t, const float* __restrict__ b2,
    const int* __restrict__ counts, const int* __restrict__ offs,
    const int* __restrict__ ltok, const float* __restrict__ lsc,
    float* __restrict__ out, int T)
{
    int e = blockIdx.x;
    int n = counts[e];
    int mbase = blockIdx.y * 128;
    if (mbase >= n) return;
    int nb = blockIdx.z & 3, kb = blockIdx.z >> 2;
    int db = nb * 128;
    int off = offs[e];

    __shared__ __align__(16) unsigned char HsB[128 * 128];
    __shared__ __align__(16) unsigned char WsB[128 * 128];
    __shared__ int   toks_s[128];
    __shared__ float scs_s[128];

    int tid = threadIdx.x, lane = tid & 63, w = tid >> 6;
    int wr = w & 1, wc = w >> 1;

    if (tid < 128) {
        int idx = mbase + tid; if (idx > n - 1) idx = n - 1;
        toks_s[tid] = ltok[(size_t)e * T + idx];
        scs_s [tid] = lsc [(size_t)e * T + idx];
    }
    __syncthreads();

    const unsigned short* W2te = W2t + (size_t)e * D_MODEL * D_FF;
    int c = lane & 7, rsub = lane >> 3;

    const char* aptr[4]; const char* bptr[4]; int soff[4];
#pragma unroll
    for (int j = 0; j < 4; j++) {
        int r = j * 32 + w * 8 + rsub;
        int srow = mbase + r; if (srow > n - 1) srow = n - 1;
        int sc = c ^ (r & 7);
        aptr[j] = (const char*)(Hg + (size_t)(off + srow) * D_FF) + sc * 16;
        bptr[j] = (const char*)(W2te + (size_t)(db + r) * D_FF) + sc * 16;
        soff[j] = (j * 32 + w * 8) * 128;
    }

    f32x4 acc[4][4];
#pragma unroll
    for (int i = 0; i < 4; i++)
#pragma unroll
        for (int j = 0; j < 4; j++) acc[i][j] = (f32x4){0.f, 0.f, 0.f, 0.f};

    int kbase = kb * 1024;
    for (int kc = 0; kc < 1024; kc += 64) {
        int kabs = kbase + kc;
#pragma unroll
        for (int j = 0; j < 4; j++) gload_lds16(aptr[j] + kabs * 2, HsB + soff[j]);
#pragma unroll
        for (int j = 0; j < 4; j++) gload_lds16(bptr[j] + kabs * 2, WsB + soff[j]);
        __syncthreads();

#pragma unroll
        for (int ks = 0; ks < 2; ks++) {
            bf16x8 av[4], bv[4];
            int kbyte = ks * 64 + ((lane >> 4) * 16);
#pragma unroll
            for (int i = 0; i < 4; i++) {
                int row = wr * 64 + i * 16 + (lane & 15);
                av[i] = *(const bf16x8*)(HsB + row * 128 + (kbyte ^ ((row & 7) << 4)));
            }
#pragma unroll
            for (int j = 0; j < 4; j++) {
                int dr = wc * 64 + j * 16 + (lane & 15);
                bv[j] = *(const bf16x8*)(WsB + dr * 128 + (kbyte ^ ((dr & 7) << 4)));
            }
#pragma unroll
            for (int i = 0; i < 4; i++)
#pragma unroll
                for (int j = 0; j < 4; j++)
                    acc[i][j] = __builtin_amdgcn_mfma_f32_16x16x32_bf16(av[i], bv[j], acc[i][j], 0, 0, 0);
        }
        __syncthreads();
    }

#pragma unroll
    for (int j = 0; j < 4; j++) {
        int dg = db + wc * 64 + j * 16 + (lane & 15);
        float b2v = (kb == 0) ? b2[(size_t)e * D_MODEL + dg] : 0.f;
#pragma unroll
        for (int i = 0; i < 4; i++) {
#pragma unroll
            for (int r = 0; r < 4; r++) {
                int rowm = wr * 64 + i * 16 + (lane >> 4) * 4 + r;
                if (mbase + rowm < n) {
                    float s = scs_s[rowm];
                    int tok = toks_s[rowm];
                    atomicAdd(out + (size_t)tok * D_MODEL + dg, s * (acc[i][j][r] + b2v));
                }
            }
        }
    }
}

// ---------------- Fallback: register-staging GEMMs (fp32 weights, small ws) ----------------
__global__ __launch_bounds__(512, 2) void moe_gemm1_rs(
    const float* __restrict__ x,
    const float* __restrict__ W1, const float* __restrict__ b1,
    const int* __restrict__ counts, const int* __restrict__ offs,
    const int* __restrict__ ltok,
    unsigned short* __restrict__ Hg, int T)
{
    int e = blockIdx.x;
    int n = counts[e];
    int mbase = blockIdx.y * 128;
    if (mbase >= n) return;
    int fb = blockIdx.z * 256;
    int off = offs[e];

    __shared__ __align__(16) unsigned char XsB[128 * 128];
    __shared__ __align__(16) unsigned char WtB[256 * 128];
    __shared__ int toks_s[128];

    int tid  = threadIdx.x;
    int lane = tid & 63;
    int w    = tid >> 6;
    int wr   = w & 1, wc = w >> 1;

    if (tid < 128) {
        int idx = mbase + tid; if (idx > n - 1) idx = n - 1;
        toks_s[tid] = ltok[(size_t)e * T + idx];
    }
    __syncthreads();

    const float* W1e = W1 + (size_t)e * D_MODEL * D_FF;

    f32x4 acc[4][4];
#pragma unroll
    for (int i = 0; i < 4; i++)
#pragma unroll
        for (int j = 0; j < 4; j++) acc[i][j] = (f32x4){0.f, 0.f, 0.f, 0.f};

    int fcol = tid & 255, khalf = tid >> 8;
    const float* w1col = W1e + fb + fcol;

    for (int kc = 0; kc < D_MODEL; kc += 64) {
#pragma unroll
        for (int i = 0; i < 4; i++) {
            int idx = tid + 512 * i;
            int r = idx >> 4, c4 = idx & 15;
            const float4 v = *(const float4*)(x + (size_t)toks_s[r] * D_MODEL + kc + c4 * 4);
            *(uint2*)(XsB + r * 128 + ((c4 * 8) ^ ((r & 7) << 4))) =
                make_uint2(pk(v.x, v.y), pk(v.z, v.w));
        }
#pragma unroll
        for (int j = 0; j < 8; j++) {
            int q  = khalf * 8 + j;
            int k0 = kc + q * 4;
            float a0 = w1col[(size_t)(k0    ) * D_FF];
            float a1 = w1col[(size_t)(k0 + 1) * D_FF];
            float a2 = w1col[(size_t)(k0 + 2) * D_FF];
            float a3 = w1col[(size_t)(k0 + 3) * D_FF];
            *(uint2*)(WtB + fcol * 128 + ((q * 8) ^ ((fcol & 7) << 4))) =
                make_uint2(pk(a0, a1), pk(a2, a3));
        }
        __syncthreads();

#pragma unroll
        for (int ks = 0; ks < 2; ks++) {
            bf16x8 av[4], bv[4];
            int kbyte = ks * 64 + ((lane >> 4) * 16);
#pragma unroll
            for (int i = 0; i < 4; i++) {
                int row = wr * 64 + i * 16 + (lane & 15);
                av[i] = *(const bf16x8*)(XsB + row * 128 + (kbyte ^ ((row & 7) << 4)));
            }
#pragma unroll
            for (int j = 0; j < 4; j++) {
                int fr = wc * 64 + j * 16 + (lane & 15);
                bv[j] = *(const bf16x8*)(WtB + fr * 128 + (kbyte ^ ((fr & 7) << 4)));
            }
#pragma unroll
            for (int i = 0; i < 4; i++)
#pragma unroll
                for (int j = 0; j < 4; j++)
                    acc[i][j] = __builtin_amdgcn_mfma_f32_16x16x32_bf16(av[i], bv[j], acc[i][j], 0, 0, 0);
        }
        __syncthreads();
    }

    const float* b1e = b1 + (size_t)e * D_FF;
#pragma unroll
    for (int j = 0; j < 4; j++) {
        int fg = fb + wc * 64 + j * 16 + (lane & 15);
        float b1v = b1e[fg];
#pragma unroll
        for (int i = 0; i < 4; i++) {
#pragma unroll
            for (int r = 0; r < 4; r++) {
                int rowm = wr * 64 + i * 16 + (lane >> 4) * 4 + r;
                if (mbase + rowm < n) {
                    float v = gelu_exact(acc[i][j][r] + b1v);
                    Hg[(size_t)(off + mbase + rowm) * D_FF + fg] = f2bf(v);
                }
            }
        }
    }
}

__global__ __launch_bounds__(512, 2) void moe_gemm2_rs(
    const unsigned short* __restrict__ Hg,
    const float* __restrict__ W2, const float* __restrict__ b2,
    const int* __restrict__ counts, const int* __restrict__ offs,
    const int* __restrict__ ltok, const float* __restrict__ lsc,
    float* __restrict__ out, int T)
{
    int e = blockIdx.x;
    int n = counts[e];
    int mbase = blockIdx.y * 128;
    if (mbase >= n) return;
    int nb = blockIdx.z & 1, kb = blockIdx.z >> 1;
    int db = nb * 256;
    int off = offs[e];

    __shared__ __align__(16) unsigned char HsB[128 * 128];
    __shared__ __align__(16) unsigned char WtB[256 * 128];
    __shared__ int   toks_s[128];
    __shared__ float scs_s[128];

    int tid  = threadIdx.x;
    int lane = tid & 63;
    int w    = tid >> 6;
    int wr   = w & 1, wc = w >> 1;

    if (tid < 128) {
        int idx = mbase + tid; if (idx > n - 1) idx = n - 1;
        toks_s[tid] = ltok[(size_t)e * T + idx];
        scs_s [tid] = lsc [(size_t)e * T + idx];
    }
    __syncthreads();

    const float* W2e = W2 + (size_t)e * D_FF * D_MODEL;

    f32x4 acc[4][4];
#pragma unroll
    for (int i = 0; i < 4; i++)
#pragma unroll
        for (int j = 0; j < 4; j++) acc[i][j] = (f32x4){0.f, 0.f, 0.f, 0.f};

    int dcol = tid & 255, khalf = tid >> 8;
    const float* w2col = W2e + db + dcol;

    for (int kc = 0; kc < 1024; kc += 64) {
        int kabs = kb * 1024 + kc;
#pragma unroll
        for (int i = 0; i < 2; i++) {
            int idx = tid + 512 * i;
            int r = idx >> 3, c16 = idx & 7;
            int srow = mbase + r; if (srow > n - 1) srow = n - 1;
            const uint4 v = *(const uint4*)(Hg + (size_t)(off + srow) * D_FF + kabs + c16 * 8);
            *(uint4*)(HsB + r * 128 + ((c16 * 16) ^ ((r & 7) << 4))) = v;
        }
#pragma unroll
        for (int j = 0; j < 8; j++) {
            int q  = khalf * 8 + j;
            int k0 = kabs + q * 4;
            float a0 = w2col[(size_t)(k0    ) * D_MODEL];
            float a1 = w2col[(size_t)(k0 + 1) * D_MODEL];
            float a2 = w2col[(size_t)(k0 + 2) * D_MODEL];
            float a3 = w2col[(size_t)(k0 + 3) * D_MODEL];
            *(uint2*)(WtB + dcol * 128 + ((q * 8) ^ ((dcol & 7) << 4))) =
                make_uint2(pk(a0, a1), pk(a2, a3));
        }
        __syncthreads();

#pragma unroll
        for (int ks = 0; ks < 2; ks++) {
            bf16x8 av[4], bv[4];
            int kbyte = ks * 64 + ((lane >> 4) * 16);
#pragma unroll
            for (int i = 0; i < 4; i++) {
                int row = wr * 64 + i * 16 + (lane & 15);
                av[i] = *(const bf16x8*)(HsB + row * 128 + (kbyte ^ ((row & 7) << 4)));
            }
#pragma unroll
            for (int j = 0; j < 4; j++) {
                int dr = wc * 64 + j * 16 + (lane & 15);
                bv[j] = *(const bf16x8*)(WtB + dr * 128 + (kbyte ^ ((dr & 7) << 4)));
            }
#pragma unroll
            for (int i = 0; i < 4; i++)
#pragma unroll
                for (int j = 0; j < 4; j++)
                    acc[i][j] = __builtin_amdgcn_mfma_f32_16x16x32_bf16(av[i], bv[j], acc[i][j], 0, 0, 0);
        }
        __syncthreads();
    }

#pragma unroll
    for (int j = 0; j < 4; j++) {
        int dg = db + wc * 64 + j * 16 + (lane & 15);
        float b2v = (kb == 0) ? b2[(size_t)e * D_MODEL + dg] : 0.f;
#pragma unroll
        for (int i = 0; i < 4; i++) {
#pragma unroll
            for (int r = 0; r < 4; r++) {
                int rowm = wr * 64 + i * 16 + (lane >> 4) * 4 + r;
                if (mbase + rowm < n) {
                    float s = scs_s[rowm];
                    int tok = toks_s[rowm];
                    atomicAdd(out + (size_t)tok * D_MODEL + dg, s * (acc[i][j][r] + b2v));
                }
            }
        }
    }
}

extern "C" void kernel_launch(void* const* d_in, const int* in_sizes, int n_in,
                              void* d_out, int out_size, void* d_ws, size_t ws_size,
                              hipStream_t stream)
{
    const float* x  = (const float*)d_in[0];
    const float* Wg = (const float*)d_in[1];
    const float* bg = (const float*)d_in[2];
    const float* W1 = (const float*)d_in[3];
    const float* b1 = (const float*)d_in[4];
    const float* W2 = (const float*)d_in[5];
    const float* b2 = (const float*)d_in[6];
    float* out = (float*)d_out;
    int T = in_sizes[0] / D_MODEL;  // 4096

    // base region (< 512 KB)
    int*    counts = (int*)d_ws;
    int*    offs   = (int*)((char*)d_ws + 64);
    int*    ltok   = (int*)((char*)d_ws + 256);
    float*  lsc    = (float*)((char*)d_ws + 256 + (size_t)NEXP * T * sizeof(int));
    int2*   tk_e   = (int2*)((char*)d_ws + 256 + (size_t)2 * NEXP * T * sizeof(int));
    float2* tk_s   = (float2*)((char*)tk_e + (size_t)T * sizeof(int2));
    int2*   tk_pos = (int2*)((char*)tk_s + (size_t)T * sizeof(float2));

    const size_t Hoff   = 512 * 1024;
    const size_t Hbytes = (size_t)2 * T * D_FF * sizeof(unsigned short);
    const size_t Xoff   = Hoff + Hbytes;
    const size_t Xbytes = (size_t)T * D_MODEL * sizeof(unsigned short);
    const size_t W1off  = Xoff + Xbytes;
    const size_t Wbytes = (size_t)NEXP * D_MODEL * D_FF * sizeof(unsigned short);
    const size_t W2off  = W1off + Wbytes;
    const size_t Ogoff  = W2off + Wbytes;
    const size_t Ogbytes = (size_t)2 * (2 * T) * D_MODEL * sizeof(float);
    const size_t need_og   = Ogoff + Ogbytes + 4096;
    const size_t need_full = W2off + Wbytes + 4096;
    const size_t need_r2   = Hoff + Hbytes + 4096;

    bool og   = ws_size >= need_og;
    bool full = ws_size >= need_full;
    unsigned short* Xb = full ? (unsigned short*)((char*)d_ws + Xoff) : nullptr;

    hipMemsetAsync(d_ws, 0, 256, stream);
    if (!og)
        hipMemsetAsync(d_out, 0, (size_t)out_size * sizeof(float), stream);

    gate_kernel<<<dim3((T + 3) / 4), dim3(256), 0, stream>>>(
        x, Wg, bg, tk_e, tk_s, Xb, T);
    route_kernel<<<dim3((T + 255) / 256), dim3(256), 0, stream>>>(
        tk_e, tk_s, counts, ltok, lsc, tk_pos, T);
    prefix_kernel<<<dim3(1), dim3(64), 0, stream>>>(counts, offs);

    if (full) {
        unsigned short* Hg  = (unsigned short*)((char*)d_ws + Hoff);
        unsigned short* W1t = (unsigned short*)((char*)d_ws + W1off);
        unsigned short* W2t = (unsigned short*)((char*)d_ws + W2off);

        tcvt_kernel<<<dim3(D_FF / 64, D_MODEL / 64, NEXP), dim3(256), 0, stream>>>(
            W1, W1t, D_MODEL, D_FF);
        tcvt_kernel<<<dim3(D_MODEL / 64, D_FF / 64, NEXP), dim3(256), 0, stream>>>(
            W2, W2t, D_FF, D_MODEL);

        int ytiles = (T + 127) / 128;   // 32
        int g1 = NEXP * ytiles * (D_FF / 128);   // 4096, %8==0
        moe_gemm1<<<dim3(g1), dim3(256), 0, stream>>>(
            Xb, W1t, b1, counts, offs, ltok, Hg, T);

        if (og) {
            float* Og = (float*)((char*)d_ws + Ogoff);
            int mtiles = (T + 63) / 64;          // 64
            int g2 = NEXP * mtiles * 8;          // 4096, %8==0
            moe_gemm2_og<<<dim3(g2), dim3(256), 0, stream>>>(
                Hg, W2t, b2, counts, offs, ltok, lsc, Og, T);
            combine_kernel<<<dim3((T + 3) / 4), dim3(256), 0, stream>>>(
                Og, offs, tk_pos, out, T);
        } else {
            moe_gemm2<<<dim3(NEXP, ytiles, 8), dim3(256), 0, stream>>>(
                Hg, W2t, b2, counts, offs, ltok, lsc, out, T);
        }
    } else if (ws_size >= need_r2) {
        unsigned short* Hg = (unsigned short*)((char*)d_ws + Hoff);
        moe_gemm1_rs<<<dim3(NEXP, (T + 127) / 128, D_FF / 256), dim3(512), 0, stream>>>(
            x, W1, b1, counts, offs, ltok, Hg, T);
        moe_gemm2_rs<<<dim3(NEXP, (T + 127) / 128, 4), dim3(512), 0, stream>>>(
            Hg, W2, b2, counts, offs, ltok, lsc, out, T);
    }
}

// Round 14
// 123.885 us; speedup vs baseline: 1.0919x; 1.0919x over previous
//
#include <hip/hip_runtime.h>
#include <hip/hip_bf16.h>
#include <math.h>

#define D_MODEL 512
#define D_FF    2048
#define NEXP    8
#define NXCD    8

using bf16x8 = __attribute__((ext_vector_type(8))) short;
using f32x4  = __attribute__((ext_vector_type(4))) float;

__device__ inline unsigned short f2bf(float x) {
    __hip_bfloat16 h = __float2bfloat16(x);
    unsigned short u; __builtin_memcpy(&u, &h, 2); return u;
}
__device__ inline unsigned pk(float a, float b) {
    return (unsigned)f2bf(a) | ((unsigned)f2bf(b) << 16);
}
// A&S 7.1.26 rational erf, |err| <= 1.5e-7 (invisible at bf16 output)
__device__ inline float erf_fast(float x) {
    float ax = fabsf(x);
    float t  = 1.f / fmaf(0.3275911f, ax, 1.f);
    float p  = t * fmaf(t, fmaf(t, fmaf(t, fmaf(t, 1.061405429f, -1.453152027f),
                                        1.421413741f), -0.284496736f), 0.254829592f);
    float r  = 1.f - p * __expf(-ax * ax);
    return copysignf(r, x);
}
__device__ inline float gelu_exact(float v) {
    return 0.5f * v * (1.f + erf_fast(v * 0.70710678118654752f));
}
__device__ inline void gload_lds16(const void* g, void* l) {
    __builtin_amdgcn_global_load_lds(
        (const __attribute__((address_space(1))) unsigned int*)g,
        (__attribute__((address_space(3))) unsigned int*)l, 16, 0, 0);
}

// ---------------- Gating: one wave per token, NO atomics ----------------
__global__ __launch_bounds__(256) void gate_kernel(
    const float* __restrict__ x, const float* __restrict__ Wg,
    const float* __restrict__ bg,
    int2* __restrict__ tk_e, float2* __restrict__ tk_s,
    unsigned short* __restrict__ Xb, int T)
{
    int lane = threadIdx.x & 63;
    int w    = threadIdx.x >> 6;
    int t    = blockIdx.x * 4 + w;
    if (t >= T) return;

    const float* xr = x + (size_t)t * D_MODEL;
    unsigned short* xbr = Xb ? (Xb + (size_t)t * D_MODEL) : nullptr;
    float lg[NEXP];
#pragma unroll
    for (int e = 0; e < NEXP; e++) lg[e] = 0.f;

#pragma unroll
    for (int it = 0; it < D_MODEL / 64; it++) {
        int d = lane + 64 * it;
        float xv = xr[d];
        if (xbr) xbr[d] = f2bf(xv);
        const float* wr = Wg + (size_t)d * NEXP;
#pragma unroll
        for (int e = 0; e < NEXP; e++) lg[e] += xv * wr[e];
    }
#pragma unroll
    for (int off = 32; off > 0; off >>= 1) {
#pragma unroll
        for (int e = 0; e < NEXP; e++) lg[e] += __shfl_xor(lg[e], off, 64);
    }

    if (lane == 0) {
#pragma unroll
        for (int e = 0; e < NEXP; e++) lg[e] += bg[e];
        int e0 = 0;
#pragma unroll
        for (int e = 1; e < NEXP; e++) if (lg[e] > lg[e0]) e0 = e;
        int e1 = (e0 == 0) ? 1 : 0;
#pragma unroll
        for (int e = 0; e < NEXP; e++) if (e != e0 && lg[e] > lg[e1]) e1 = e;
        float s0 = 1.f / (1.f + expf(lg[e1] - lg[e0]));
        tk_e[t] = make_int2(e0, e1);
        tk_s[t] = make_float2(s0, 1.f - s0);
    }
}

// ---------------- Routing: wave-aggregated list append + slot record ----------------
__global__ __launch_bounds__(256) void route_kernel(
    const int2* __restrict__ tk_e, const float2* __restrict__ tk_s,
    int* __restrict__ counts, int* __restrict__ ltok, float* __restrict__ lsc,
    int2* __restrict__ tk_pos, int T)
{
    int t    = blockIdx.x * 256 + threadIdx.x;
    int lane = threadIdx.x & 63;
    bool valid = t < T;
    int2   es = valid ? tk_e[t] : make_int2(-1, -1);
    float2 ss = valid ? tk_s[t] : make_float2(0.f, 0.f);
    int ppos[2] = {0, 0};

#pragma unroll
    for (int slot = 0; slot < 2; slot++) {
        int   e = slot ? es.y : es.x;
        float s = slot ? ss.y : ss.x;
#pragma unroll
        for (int ex = 0; ex < NEXP; ex++) {
            unsigned long long m = __ballot(e == ex);
            if (m == 0ull) continue;
            int leader = __ffsll((long long)m) - 1;
            int base = 0;
            if (lane == leader) base = atomicAdd(&counts[ex], __popcll(m));
            base = __shfl(base, leader, 64);
            if (e == ex) {
                int pos = base + __popcll(m & ((1ull << lane) - 1ull));
                ltok[(size_t)ex * T + pos] = t;
                lsc [(size_t)ex * T + pos] = s;
                ppos[slot] = pos | (ex << 16);
            }
        }
    }
    if (valid) tk_pos[t] = make_int2(ppos[0], ppos[1]);
}

__global__ void prefix_kernel(const int* __restrict__ counts, int* __restrict__ offs)
{
    if (threadIdx.x == 0) {
        int acc = 0;
        for (int e = 0; e < NEXP; e++) { offs[e] = acc; acc += counts[e]; }
        offs[NEXP] = acc;
    }
}

// ------- Transpose-convert BOTH weights in ONE launch: [e][R][C] f32 -> [e][C][R] bf16
// grid (256, 16): y in [0,8) -> W1 (R=512,C=2048, 8x32=256 tiles);
//                 y in [8,16) -> W2 (R=2048,C=512, 32x8=256 tiles).
__global__ __launch_bounds__(256) void tcvt2_kernel(
    const float* __restrict__ W1, const float* __restrict__ W2,
    unsigned short* __restrict__ W1t, unsigned short* __restrict__ W2t)
{
    __shared__ unsigned short tile[64][72];
    int z = blockIdx.y;
    bool isw2 = z >= NEXP;
    int e = z & (NEXP - 1);
    int R = isw2 ? D_FF : D_MODEL;
    int C = isw2 ? D_MODEL : D_FF;
    const float* src = isw2 ? W2 : W1;
    unsigned short* dst = isw2 ? W2t : W1t;

    int nx  = C / 64;
    int lin = blockIdx.x;
    int r0 = (lin / nx) * 64, c0 = (lin % nx) * 64;

    const float* s = src + ((size_t)e * R + r0) * C + c0;
    unsigned short* d = dst + ((size_t)e * C + c0) * R + r0;
    int t = threadIdx.x;
#pragma unroll
    for (int i = 0; i < 4; i++) {
        int idx = t + 256 * i;
        int r = idx >> 4, c4 = (idx & 15) * 4;
        float4 v = *(const float4*)(s + (size_t)r * C + c4);
        tile[c4    ][r] = f2bf(v.x);
        tile[c4 + 1][r] = f2bf(v.y);
        tile[c4 + 2][r] = f2bf(v.z);
        tile[c4 + 3][r] = f2bf(v.w);
    }
    __syncthreads();
#pragma unroll
    for (int i = 0; i < 2; i++) {
        int idx = t + 256 * i;
        int c = idx >> 3, q = idx & 7;
        uint4 v = *(const uint4*)(&tile[c][q * 8]);
        *(uint4*)(d + (size_t)c * R + q * 8) = v;
    }
}

// ---------------- GEMM1: H = gelu(Xb @ W1t^T + b1) ----------------
// R12 (unchanged): 128x128, 4 waves, 2 barriers/step, XCD swizzle.
__global__ __launch_bounds__(256, 4) void moe_gemm1(
    const unsigned short* __restrict__ Xb,
    const unsigned short* __restrict__ W1t, const float* __restrict__ b1,
    const int* __restrict__ counts, const int* __restrict__ offs,
    const int* __restrict__ ltok,
    unsigned short* __restrict__ Hg, int T)
{
    int nwg  = gridDim.x;
    int bid  = blockIdx.x;
    int work = (bid % NXCD) * (nwg / NXCD) + bid / NXCD;
    int perexp = nwg / NEXP;
    int e    = work / perexp;
    int rem  = work % perexp;
    int mbase = (rem >> 4) * 128;
    int fb    = (rem & 15) * 128;

    int n = counts[e];
    if (mbase >= n) return;
    int off = offs[e];

    __shared__ __align__(16) unsigned char SB[2][16384];
    __shared__ int toks_s[128];

    int tid = threadIdx.x, lane = tid & 63, w = tid >> 6;
    int wr = w & 1, wc = w >> 1;

    if (tid < 128) {
        int idx = mbase + tid; if (idx > n - 1) idx = n - 1;
        toks_s[tid] = ltok[(size_t)e * T + idx];
    }
    __syncthreads();

    const unsigned short* W1te = W1t + (size_t)e * D_FF * D_MODEL;
    int c = lane & 7, rsub = lane >> 3;

    const char* aptr[4]; const char* bptr[4]; int soff[4];
#pragma unroll
    for (int j = 0; j < 4; j++) {
        int r  = j * 32 + w * 8 + rsub;
        int sc = c ^ (r & 7);
        aptr[j] = (const char*)(Xb + (size_t)toks_s[r] * D_MODEL) + sc * 16;
        bptr[j] = (const char*)(W1te + (size_t)(fb + r) * D_MODEL) + sc * 16;
        soff[j] = (j * 32 + w * 8) * 128;
    }

    f32x4 acc[4][4];
#pragma unroll
    for (int i = 0; i < 4; i++)
#pragma unroll
        for (int j = 0; j < 4; j++) acc[i][j] = (f32x4){0.f, 0.f, 0.f, 0.f};

    for (int kc = 0; kc < D_MODEL; kc += 64) {
#pragma unroll
        for (int j = 0; j < 4; j++) gload_lds16(aptr[j] + kc * 2, SB[0] + soff[j]);
#pragma unroll
        for (int j = 0; j < 4; j++) gload_lds16(bptr[j] + kc * 2, SB[1] + soff[j]);
        __syncthreads();

#pragma unroll
        for (int ks = 0; ks < 2; ks++) {
            bf16x8 av[4], bv[4];
            int kbyte = ks * 64 + ((lane >> 4) * 16);
#pragma unroll
            for (int i = 0; i < 4; i++) {
                int row = wr * 64 + i * 16 + (lane & 15);
                av[i] = *(const bf16x8*)(SB[0] + row * 128 + (kbyte ^ ((row & 7) << 4)));
            }
#pragma unroll
            for (int j = 0; j < 4; j++) {
                int fr = wc * 64 + j * 16 + (lane & 15);
                bv[j] = *(const bf16x8*)(SB[1] + fr * 128 + (kbyte ^ ((fr & 7) << 4)));
            }
#pragma unroll
            for (int i = 0; i < 4; i++)
#pragma unroll
                for (int j = 0; j < 4; j++)
                    acc[i][j] = __builtin_amdgcn_mfma_f32_16x16x32_bf16(av[i], bv[j], acc[i][j], 0, 0, 0);
        }
        __syncthreads();
    }

    // epilogue: bias+GELU -> swizzled LDS (bf16) -> coalesced uint4 stores
    char* Eb = (char*)&SB[0][0];
    const float* b1e = b1 + (size_t)e * D_FF;
#pragma unroll
    for (int j = 0; j < 4; j++) {
        int col = wc * 64 + j * 16 + (lane & 15);
        float b1v = b1e[fb + col];
#pragma unroll
        for (int i = 0; i < 4; i++) {
#pragma unroll
            for (int r = 0; r < 4; r++) {
                int row = wr * 64 + i * 16 + (lane >> 4) * 4 + r;
                float v = gelu_exact(acc[i][j][r] + b1v);
                *(unsigned short*)(Eb + row * 256 + ((col * 2) ^ ((row & 7) << 4))) = f2bf(v);
            }
        }
    }
    __syncthreads();
#pragma unroll
    for (int k = 0; k < 8; k++) {
        int idx = tid + 256 * k;
        int row = idx >> 4, ch = idx & 15;
        if (mbase + row < n) {
            uint4 v = *(const uint4*)(Eb + row * 256 + ((ch * 16) ^ ((row & 7) << 4)));
            *(uint4*)(Hg + (size_t)(off + mbase + row) * D_FF + fb + ch * 8) = v;
        }
    }
}

// ---------------- GEMM2 (atomic-free): Og[kb][slot][d] = s*(H@W2t^T + b2) ----------------
// R12 (unchanged): 128 M-tile, ksplit=2, 4 waves, XCD swizzle.
__global__ __launch_bounds__(256, 4) void moe_gemm2_og(
    const unsigned short* __restrict__ Hg,
    const unsigned short* __restrict__ W2t, const float* __restrict__ b2,
    const int* __restrict__ counts, const int* __restrict__ offs,
    const int* __restrict__ ltok, const float* __restrict__ lsc,
    float* __restrict__ Og, int T)
{
    int nwg  = gridDim.x;
    int bid  = blockIdx.x;
    int work = (bid % NXCD) * (nwg / NXCD) + bid / NXCD;
    int perexp = nwg / NEXP;
    int e    = work / perexp;
    int rem  = work % perexp;
    int mbase = (rem >> 3) * 128;
    int z    = rem & 7;
    int nb   = z & 3, kb = z >> 2;
    int db   = nb * 128;

    int n = counts[e];
    if (mbase >= n) return;
    int off = offs[e];

    __shared__ __align__(16) unsigned char HsB[128 * 128];
    __shared__ __align__(16) unsigned char WsB[128 * 128];
    __shared__ float scs_s[128];

    int tid = threadIdx.x, lane = tid & 63, w = tid >> 6;
    int wr = w & 1, wc = w >> 1;

    if (tid < 128) {
        int idx = mbase + tid; if (idx > n - 1) idx = n - 1;
        scs_s[tid] = lsc[(size_t)e * T + idx];
    }
    __syncthreads();

    const unsigned short* W2te = W2t + (size_t)e * D_MODEL * D_FF;
    int c = lane & 7, rsub = lane >> 3;

    const char* aptr[4]; const char* bptr[4]; int soff[4];
#pragma unroll
    for (int j = 0; j < 4; j++) {
        int r = j * 32 + w * 8 + rsub;
        int srow = mbase + r; if (srow > n - 1) srow = n - 1;
        int sc = c ^ (r & 7);
        aptr[j] = (const char*)(Hg + (size_t)(off + srow) * D_FF) + sc * 16;
        bptr[j] = (const char*)(W2te + (size_t)(db + r) * D_FF) + sc * 16;
        soff[j] = (j * 32 + w * 8) * 128;
    }

    f32x4 acc[4][4];
#pragma unroll
    for (int i = 0; i < 4; i++)
#pragma unroll
        for (int j = 0; j < 4; j++) acc[i][j] = (f32x4){0.f, 0.f, 0.f, 0.f};

    int kbase = kb * 1024;
    for (int kc = 0; kc < 1024; kc += 64) {
        int kabs = kbase + kc;
#pragma unroll
        for (int j = 0; j < 4; j++) gload_lds16(aptr[j] + kabs * 2, HsB + soff[j]);
#pragma unroll
        for (int j = 0; j < 4; j++) gload_lds16(bptr[j] + kabs * 2, WsB + soff[j]);
        __syncthreads();

#pragma unroll
        for (int ks = 0; ks < 2; ks++) {
            bf16x8 av[4], bv[4];
            int kbyte = ks * 64 + ((lane >> 4) * 16);
#pragma unroll
            for (int i = 0; i < 4; i++) {
                int row = wr * 64 + i * 16 + (lane & 15);
                av[i] = *(const bf16x8*)(HsB + row * 128 + (kbyte ^ ((row & 7) << 4)));
            }
#pragma unroll
            for (int j = 0; j < 4; j++) {
                int dr = wc * 64 + j * 16 + (lane & 15);
                bv[j] = *(const bf16x8*)(WsB + dr * 128 + (kbyte ^ ((dr & 7) << 4)));
            }
#pragma unroll
            for (int i = 0; i < 4; i++)
#pragma unroll
                for (int j = 0; j < 4; j++)
                    acc[i][j] = __builtin_amdgcn_mfma_f32_16x16x32_bf16(av[i], bv[j], acc[i][j], 0, 0, 0);
        }
        __syncthreads();
    }

    // plain coalesced-granule stores; kb planes disjoint -> no race, no atomics
    float* Ogk = Og + (size_t)kb * (2 * T) * D_MODEL;
#pragma unroll
    for (int j = 0; j < 4; j++) {
        int dg = db + wc * 64 + j * 16 + (lane & 15);
        float b2v = (kb == 0) ? b2[(size_t)e * D_MODEL + dg] : 0.f;
#pragma unroll
        for (int i = 0; i < 4; i++) {
#pragma unroll
            for (int r = 0; r < 4; r++) {
                int rowm = wr * 64 + i * 16 + (lane >> 4) * 4 + r;
                if (mbase + rowm < n) {
                    float s = scs_s[rowm];
                    Ogk[(size_t)(off + mbase + rowm) * D_MODEL + dg] = s * (acc[i][j][r] + b2v);
                }
            }
        }
    }
}

// ---------------- Combine: out[t] = sum of 4 partial rows ----------------
__global__ __launch_bounds__(256) void combine_kernel(
    const float* __restrict__ Og, const int* __restrict__ offs,
    const int2* __restrict__ tk_pos, float* __restrict__ out, int T)
{
    int w = threadIdx.x >> 6, lane = threadIdx.x & 63;
    int t = blockIdx.x * 4 + w;
    if (t >= T) return;
    int2 p = tk_pos[t];
    int sA = offs[p.x >> 16] + (p.x & 0xffff);
    int sB = offs[p.y >> 16] + (p.y & 0xffff);
    size_t S = (size_t)(2 * T) * D_MODEL;
    const float4* r0 = (const float4*)(Og + (size_t)sA * D_MODEL);
    const float4* r1 = (const float4*)(Og + S + (size_t)sA * D_MODEL);
    const float4* r2 = (const float4*)(Og + (size_t)sB * D_MODEL);
    const float4* r3 = (const float4*)(Og + S + (size_t)sB * D_MODEL);
    float4* o = (float4*)(out + (size_t)t * D_MODEL);
#pragma unroll
    for (int i = 0; i < 2; i++) {
        int idx = lane + 64 * i;
        float4 a = r0[idx], b = r1[idx], cc = r2[idx], d = r3[idx];
        o[idx] = make_float4(a.x + b.x + cc.x + d.x, a.y + b.y + cc.y + d.y,
                             a.z + b.z + cc.z + d.z, a.w + b.w + cc.w + d.w);
    }
}

// ---------------- GEMM2 (atomic fallback, small-ws path) ----------------
__global__ __launch_bounds__(256, 4) void moe_gemm2(
    const unsigned short* __restrict__ Hg,
    const unsigned short* __restrict__ W2t, const float* __restrict__ b2,
    const int* __restrict__ counts, const int* __restrict__ offs,
    const int* __restrict__ ltok, const float* __restrict__ lsc,
    float* __restrict__ out, int T)
{
    int e = blockIdx.x;
    int n = counts[e];
    int mbase = blockIdx.y * 128;
    if (mbase >= n) return;
    int nb = blockIdx.z & 3, kb = blockIdx.z >> 2;
    int db = nb * 128;
    int off = offs[e];

    __shared__ __align__(16) unsigned char HsB[128 * 128];
    __shared__ __align__(16) unsigned char WsB[128 * 128];
    __shared__ int   toks_s[128];
    __shared__ float scs_s[128];

    int tid = threadIdx.x, lane = tid & 63, w = tid >> 6;
    int wr = w & 1, wc = w >> 1;

    if (tid < 128) {
        int idx = mbase + tid; if (idx > n - 1) idx = n - 1;
        toks_s[tid] = ltok[(size_t)e * T + idx];
        scs_s [tid] = lsc [(size_t)e * T + idx];
    }
    __syncthreads();

    const unsigned short* W2te = W2t + (size_t)e * D_MODEL * D_FF;
    int c = lane & 7, rsub = lane >> 3;

    const char* aptr[4]; const char* bptr[4]; int soff[4];
#pragma unroll
    for (int j = 0; j < 4; j++) {
        int r = j * 32 + w * 8 + rsub;
        int srow = mbase + r; if (srow > n - 1) srow = n - 1;
        int sc = c ^ (r & 7);
        aptr[j] = (const char*)(Hg + (size_t)(off + srow) * D_FF) + sc * 16;
        bptr[j] = (const char*)(W2te + (size_t)(db + r) * D_FF) + sc * 16;
        soff[j] = (j * 32 + w * 8) * 128;
    }

    f32x4 acc[4][4];
#pragma unroll
    for (int i = 0; i < 4; i++)
#pragma unroll
        for (int j = 0; j < 4; j++) acc[i][j] = (f32x4){0.f, 0.f, 0.f, 0.f};

    int kbase = kb * 1024;
    for (int kc = 0; kc < 1024; kc += 64) {
        int kabs = kbase + kc;
#pragma unroll
        for (int j = 0; j < 4; j++) gload_lds16(aptr[j] + kabs * 2, HsB + soff[j]);
#pragma unroll
        for (int j = 0; j < 4; j++) gload_lds16(bptr[j] + kabs * 2, WsB + soff[j]);
        __syncthreads();

#pragma unroll
        for (int ks = 0; ks < 2; ks++) {
            bf16x8 av[4], bv[4];
            int kbyte = ks * 64 + ((lane >> 4) * 16);
#pragma unroll
            for (int i = 0; i < 4; i++) {
                int row = wr * 64 + i * 16 + (lane & 15);
                av[i] = *(const bf16x8*)(HsB + row * 128 + (kbyte ^ ((row & 7) << 4)));
            }
#pragma unroll
            for (int j = 0; j < 4; j++) {
                int dr = wc * 64 + j * 16 + (lane & 15);
                bv[j] = *(const bf16x8*)(WsB + dr * 128 + (kbyte ^ ((dr & 7) << 4)));
            }
#pragma unroll
            for (int i = 0; i < 4; i++)
#pragma unroll
                for (int j = 0; j < 4; j++)
                    acc[i][j] = __builtin_amdgcn_mfma_f32_16x16x32_bf16(av[i], bv[j], acc[i][j], 0, 0, 0);
        }
        __syncthreads();
    }

#pragma unroll
    for (int j = 0; j < 4; j++) {
        int dg = db + wc * 64 + j * 16 + (lane & 15);
        float b2v = (kb == 0) ? b2[(size_t)e * D_MODEL + dg] : 0.f;
#pragma unroll
        for (int i = 0; i < 4; i++) {
#pragma unroll
            for (int r = 0; r < 4; r++) {
                int rowm = wr * 64 + i * 16 + (lane >> 4) * 4 + r;
                if (mbase + rowm < n) {
                    float s = scs_s[rowm];
                    int tok = toks_s[rowm];
                    atomicAdd(out + (size_t)tok * D_MODEL + dg, s * (acc[i][j][r] + b2v));
                }
            }
        }
    }
}

// ---------------- Fallback: register-staging GEMMs (fp32 weights, small ws) ----------------
__global__ __launch_bounds__(512, 2) void moe_gemm1_rs(
    const float* __restrict__ x,
    const float* __restrict__ W1, const float* __restrict__ b1,
    const int* __restrict__ counts, const int* __restrict__ offs,
    const int* __restrict__ ltok,
    unsigned short* __restrict__ Hg, int T)
{
    int e = blockIdx.x;
    int n = counts[e];
    int mbase = blockIdx.y * 128;
    if (mbase >= n) return;
    int fb = blockIdx.z * 256;
    int off = offs[e];

    __shared__ __align__(16) unsigned char XsB[128 * 128];
    __shared__ __align__(16) unsigned char WtB[256 * 128];
    __shared__ int toks_s[128];

    int tid  = threadIdx.x;
    int lane = tid & 63;
    int w    = tid >> 6;
    int wr   = w & 1, wc = w >> 1;

    if (tid < 128) {
        int idx = mbase + tid; if (idx > n - 1) idx = n - 1;
        toks_s[tid] = ltok[(size_t)e * T + idx];
    }
    __syncthreads();

    const float* W1e = W1 + (size_t)e * D_MODEL * D_FF;

    f32x4 acc[4][4];
#pragma unroll
    for (int i = 0; i < 4; i++)
#pragma unroll
        for (int j = 0; j < 4; j++) acc[i][j] = (f32x4){0.f, 0.f, 0.f, 0.f};

    int fcol = tid & 255, khalf = tid >> 8;
    const float* w1col = W1e + fb + fcol;

    for (int kc = 0; kc < D_MODEL; kc += 64) {
#pragma unroll
        for (int i = 0; i < 4; i++) {
            int idx = tid + 512 * i;
            int r = idx >> 4, c4 = idx & 15;
            const float4 v = *(const float4*)(x + (size_t)toks_s[r] * D_MODEL + kc + c4 * 4);
            *(uint2*)(XsB + r * 128 + ((c4 * 8) ^ ((r & 7) << 4))) =
                make_uint2(pk(v.x, v.y), pk(v.z, v.w));
        }
#pragma unroll
        for (int j = 0; j < 8; j++) {
            int q  = khalf * 8 + j;
            int k0 = kc + q * 4;
            float a0 = w1col[(size_t)(k0    ) * D_FF];
            float a1 = w1col[(size_t)(k0 + 1) * D_FF];
            float a2 = w1col[(size_t)(k0 + 2) * D_FF];
            float a3 = w1col[(size_t)(k0 + 3) * D_FF];
            *(uint2*)(WtB + fcol * 128 + ((q * 8) ^ ((fcol & 7) << 4))) =
                make_uint2(pk(a0, a1), pk(a2, a3));
        }
        __syncthreads();

#pragma unroll
        for (int ks = 0; ks < 2; ks++) {
            bf16x8 av[4], bv[4];
            int kbyte = ks * 64 + ((lane >> 4) * 16);
#pragma unroll
            for (int i = 0; i < 4; i++) {
                int row = wr * 64 + i * 16 + (lane & 15);
                av[i] = *(const bf16x8*)(XsB + row * 128 + (kbyte ^ ((row & 7) << 4)));
            }
#pragma unroll
            for (int j = 0; j < 4; j++) {
                int fr = wc * 64 + j * 16 + (lane & 15);
                bv[j] = *(const bf16x8*)(WtB + fr * 128 + (kbyte ^ ((fr & 7) << 4)));
            }
#pragma unroll
            for (int i = 0; i < 4; i++)
#pragma unroll
                for (int j = 0; j < 4; j++)
                    acc[i][j] = __builtin_amdgcn_mfma_f32_16x16x32_bf16(av[i], bv[j], acc[i][j], 0, 0, 0);
        }
        __syncthreads();
    }

    const float* b1e = b1 + (size_t)e * D_FF;
#pragma unroll
    for (int j = 0; j < 4; j++) {
        int fg = fb + wc * 64 + j * 16 + (lane & 15);
        float b1v = b1e[fg];
#pragma unroll
        for (int i = 0; i < 4; i++) {
#pragma unroll
            for (int r = 0; r < 4; r++) {
                int rowm = wr * 64 + i * 16 + (lane >> 4) * 4 + r;
                if (mbase + rowm < n) {
                    float v = gelu_exact(acc[i][j][r] + b1v);
                    Hg[(size_t)(off + mbase + rowm) * D_FF + fg] = f2bf(v);
                }
            }
        }
    }
}

__global__ __launch_bounds__(512, 2) void moe_gemm2_rs(
    const unsigned short* __restrict__ Hg,
    const float* __restrict__ W2, const float* __restrict__ b2,
    const int* __restrict__ counts, const int* __restrict__ offs,
    const int* __restrict__ ltok, const float* __restrict__ lsc,
    float* __restrict__ out, int T)
{
    int e = blockIdx.x;
    int n = counts[e];
    int mbase = blockIdx.y * 128;
    if (mbase >= n) return;
    int nb = blockIdx.z & 1, kb = blockIdx.z >> 1;
    int db = nb * 256;
    int off = offs[e];

    __shared__ __align__(16) unsigned char HsB[128 * 128];
    __shared__ __align__(16) unsigned char WtB[256 * 128];
    __shared__ int   toks_s[128];
    __shared__ float scs_s[128];

    int tid  = threadIdx.x;
    int lane = tid & 63;
    int w    = tid >> 6;
    int wr   = w & 1, wc = w >> 1;

    if (tid < 128) {
        int idx = mbase + tid; if (idx > n - 1) idx = n - 1;
        toks_s[tid] = ltok[(size_t)e * T + idx];
        scs_s [tid] = lsc [(size_t)e * T + idx];
    }
    __syncthreads();

    const float* W2e = W2 + (size_t)e * D_FF * D_MODEL;

    f32x4 acc[4][4];
#pragma unroll
    for (int i = 0; i < 4; i++)
#pragma unroll
        for (int j = 0; j < 4; j++) acc[i][j] = (f32x4){0.f, 0.f, 0.f, 0.f};

    int dcol = tid & 255, khalf = tid >> 8;
    const float* w2col = W2e + db + dcol;

    for (int kc = 0; kc < 1024; kc += 64) {
        int kabs = kb * 1024 + kc;
#pragma unroll
        for (int i = 0; i < 2; i++) {
            int idx = tid + 512 * i;
            int r = idx >> 3, c16 = idx & 7;
            int srow = mbase + r; if (srow > n - 1) srow = n - 1;
            const uint4 v = *(const uint4*)(Hg + (size_t)(off + srow) * D_FF + kabs + c16 * 8);
            *(uint4*)(HsB + r * 128 + ((c16 * 16) ^ ((r & 7) << 4))) = v;
        }
#pragma unroll
        for (int j = 0; j < 8; j++) {
            int q  = khalf * 8 + j;
            int k0 = kabs + q * 4;
            float a0 = w2col[(size_t)(k0    ) * D_MODEL];
            float a1 = w2col[(size_t)(k0 + 1) * D_MODEL];
            float a2 = w2col[(size_t)(k0 + 2) * D_MODEL];
            float a3 = w2col[(size_t)(k0 + 3) * D_MODEL];
            *(uint2*)(WtB + dcol * 128 + ((q * 8) ^ ((dcol & 7) << 4))) =
                make_uint2(pk(a0, a1), pk(a2, a3));
        }
        __syncthreads();

#pragma unroll
        for (int ks = 0; ks < 2; ks++) {
            bf16x8 av[4], bv[4];
            int kbyte = ks * 64 + ((lane >> 4) * 16);
#pragma unroll
            for (int i = 0; i < 4; i++) {
                int row = wr * 64 + i * 16 + (lane & 15);
                av[i] = *(const bf16x8*)(HsB + row * 128 + (kbyte ^ ((row & 7) << 4)));
            }
#pragma unroll
            for (int j = 0; j < 4; j++) {
                int dr = wc * 64 + j * 16 + (lane & 15);
                bv[j] = *(const bf16x8*)(WtB + dr * 128 + (kbyte ^ ((dr & 7) << 4)));
            }
#pragma unroll
            for (int i = 0; i < 4; i++)
#pragma unroll
                for (int j = 0; j < 4; j++)
                    acc[i][j] = __builtin_amdgcn_mfma_f32_16x16x32_bf16(av[i], bv[j], acc[i][j], 0, 0, 0);
        }
        __syncthreads();
    }

#pragma unroll
    for (int j = 0; j < 4; j++) {
        int dg = db + wc * 64 + j * 16 + (lane & 15);
        float b2v = (kb == 0) ? b2[(size_t)e * D_MODEL + dg] : 0.f;
#pragma unroll
        for (int i = 0; i < 4; i++) {
#pragma unroll
            for (int r = 0; r < 4; r++) {
                int rowm = wr * 64 + i * 16 + (lane >> 4) * 4 + r;
                if (mbase + rowm < n) {
                    float s = scs_s[rowm];
                    int tok = toks_s[rowm];
                    atomicAdd(out + (size_t)tok * D_MODEL + dg, s * (acc[i][j][r] + b2v));
                }
            }
        }
    }
}

extern "C" void kernel_launch(void* const* d_in, const int* in_sizes, int n_in,
                              void* d_out, int out_size, void* d_ws, size_t ws_size,
                              hipStream_t stream)
{
    const float* x  = (const float*)d_in[0];
    const float* Wg = (const float*)d_in[1];
    const float* bg = (const float*)d_in[2];
    const float* W1 = (const float*)d_in[3];
    const float* b1 = (const float*)d_in[4];
    const float* W2 = (const float*)d_in[5];
    const float* b2 = (const float*)d_in[6];
    float* out = (float*)d_out;
    int T = in_sizes[0] / D_MODEL;  // 4096

    // base region (< 512 KB)
    int*    counts = (int*)d_ws;
    int*    offs   = (int*)((char*)d_ws + 64);
    int*    ltok   = (int*)((char*)d_ws + 256);
    float*  lsc    = (float*)((char*)d_ws + 256 + (size_t)NEXP * T * sizeof(int));
    int2*   tk_e   = (int2*)((char*)d_ws + 256 + (size_t)2 * NEXP * T * sizeof(int));
    float2* tk_s   = (float2*)((char*)tk_e + (size_t)T * sizeof(int2));
    int2*   tk_pos = (int2*)((char*)tk_s + (size_t)T * sizeof(float2));

    const size_t Hoff   = 512 * 1024;
    const size_t Hbytes = (size_t)2 * T * D_FF * sizeof(unsigned short);
    const size_t Xoff   = Hoff + Hbytes;
    const size_t Xbytes = (size_t)T * D_MODEL * sizeof(unsigned short);
    const size_t W1off  = Xoff + Xbytes;
    const size_t Wbytes = (size_t)NEXP * D_MODEL * D_FF * sizeof(unsigned short);
    const size_t W2off  = W1off + Wbytes;
    const size_t Ogoff  = W2off + Wbytes;
    const size_t Ogbytes = (size_t)2 * (2 * T) * D_MODEL * sizeof(float);
    const size_t need_og   = Ogoff + Ogbytes + 4096;
    const size_t need_full = W2off + Wbytes + 4096;
    const size_t need_r2   = Hoff + Hbytes + 4096;

    bool og   = ws_size >= need_og;
    bool full = ws_size >= need_full;
    unsigned short* Xb = full ? (unsigned short*)((char*)d_ws + Xoff) : nullptr;

    hipMemsetAsync(d_ws, 0, 256, stream);
    if (!og)
        hipMemsetAsync(d_out, 0, (size_t)out_size * sizeof(float), stream);

    gate_kernel<<<dim3((T + 3) / 4), dim3(256), 0, stream>>>(
        x, Wg, bg, tk_e, tk_s, Xb, T);
    route_kernel<<<dim3((T + 255) / 256), dim3(256), 0, stream>>>(
        tk_e, tk_s, counts, ltok, lsc, tk_pos, T);
    prefix_kernel<<<dim3(1), dim3(64), 0, stream>>>(counts, offs);

    if (full) {
        unsigned short* Hg  = (unsigned short*)((char*)d_ws + Hoff);
        unsigned short* W1t = (unsigned short*)((char*)d_ws + W1off);
        unsigned short* W2t = (unsigned short*)((char*)d_ws + W2off);

        tcvt2_kernel<<<dim3(256, 2 * NEXP), dim3(256), 0, stream>>>(W1, W2, W1t, W2t);

        int ytiles = (T + 127) / 128;   // 32
        int g1 = NEXP * ytiles * (D_FF / 128);   // 4096, %8==0
        moe_gemm1<<<dim3(g1), dim3(256), 0, stream>>>(
            Xb, W1t, b1, counts, offs, ltok, Hg, T);

        if (og) {
            float* Og = (float*)((char*)d_ws + Ogoff);
            int g2 = NEXP * ytiles * 8;          // 2048, %8==0
            moe_gemm2_og<<<dim3(g2), dim3(256), 0, stream>>>(
                Hg, W2t, b2, counts, offs, ltok, lsc, Og, T);
            combine_kernel<<<dim3((T + 3) / 4), dim3(256), 0, stream>>>(
                Og, offs, tk_pos, out, T);
        } else {
            moe_gemm2<<<dim3(NEXP, ytiles, 8), dim3(256), 0, stream>>>(
                Hg, W2t, b2, counts, offs, ltok, lsc, out, T);
        }
    } else if (ws_size >= need_r2) {
        unsigned short* Hg = (unsigned short*)((char*)d_ws + Hoff);
        moe_gemm1_rs<<<dim3(NEXP, (T + 127) / 128, D_FF / 256), dim3(512), 0, stream>>>(
            x, W1, b1, counts, offs, ltok, Hg, T);
        moe_gemm2_rs<<<dim3(NEXP, (T + 127) / 128, 4), dim3(512), 0, stream>>>(
            Hg, W2, b2, counts, offs, ltok, lsc, out, T);
    }
}

// Round 15
// 116.359 us; speedup vs baseline: 1.1625x; 1.0647x over previous
//
#include <hip/hip_runtime.h>
#include <hip/hip_bf16.h>
#include <math.h>

#define D_MODEL 512
#define D_FF    2048
#define NEXP    8
#define NXCD    8

using bf16x8 = __attribute__((ext_vector_type(8))) short;
using f32x4  = __attribute__((ext_vector_type(4))) float;

__device__ inline unsigned short f2bf(float x) {
    __hip_bfloat16 h = __float2bfloat16(x);
    unsigned short u; __builtin_memcpy(&u, &h, 2); return u;
}
__device__ inline unsigned pk(float a, float b) {
    return (unsigned)f2bf(a) | ((unsigned)f2bf(b) << 16);
}
__device__ inline float bf2f(unsigned short u) {
    unsigned v = (unsigned)u << 16; float f; __builtin_memcpy(&f, &v, 4); return f;
}
// A&S 7.1.26 rational erf, |err| <= 1.5e-7 (invisible at bf16 output)
__device__ inline float erf_fast(float x) {
    float ax = fabsf(x);
    float t  = 1.f / fmaf(0.3275911f, ax, 1.f);
    float p  = t * fmaf(t, fmaf(t, fmaf(t, fmaf(t, 1.061405429f, -1.453152027f),
                                        1.421413741f), -0.284496736f), 0.254829592f);
    float r  = 1.f - p * __expf(-ax * ax);
    return copysignf(r, x);
}
__device__ inline float gelu_exact(float v) {
    return 0.5f * v * (1.f + erf_fast(v * 0.70710678118654752f));
}
__device__ inline void gload_lds16(const void* g, void* l) {
    __builtin_amdgcn_global_load_lds(
        (const __attribute__((address_space(1))) unsigned int*)g,
        (__attribute__((address_space(3))) unsigned int*)l, 16, 0, 0);
}
__device__ inline int off_of(const int* counts, int e) {
    int off = 0;
    for (int i = 0; i < e; i++) off += counts[i];   // e block-uniform -> scalar loads
    return off;
}

// ---------------- Gating: one wave per token, NO atomics ----------------
__global__ __launch_bounds__(256) void gate_kernel(
    const float* __restrict__ x, const float* __restrict__ Wg,
    const float* __restrict__ bg,
    int2* __restrict__ tk_e, float2* __restrict__ tk_s,
    unsigned short* __restrict__ Xb, int T)
{
    int lane = threadIdx.x & 63;
    int w    = threadIdx.x >> 6;
    int t    = blockIdx.x * 4 + w;
    if (t >= T) return;

    const float* xr = x + (size_t)t * D_MODEL;
    unsigned short* xbr = Xb ? (Xb + (size_t)t * D_MODEL) : nullptr;
    float lg[NEXP];
#pragma unroll
    for (int e = 0; e < NEXP; e++) lg[e] = 0.f;

#pragma unroll
    for (int it = 0; it < D_MODEL / 64; it++) {
        int d = lane + 64 * it;
        float xv = xr[d];
        if (xbr) xbr[d] = f2bf(xv);
        const float* wr = Wg + (size_t)d * NEXP;
#pragma unroll
        for (int e = 0; e < NEXP; e++) lg[e] += xv * wr[e];
    }
#pragma unroll
    for (int off = 32; off > 0; off >>= 1) {
#pragma unroll
        for (int e = 0; e < NEXP; e++) lg[e] += __shfl_xor(lg[e], off, 64);
    }

    if (lane == 0) {
#pragma unroll
        for (int e = 0; e < NEXP; e++) lg[e] += bg[e];
        int e0 = 0;
#pragma unroll
        for (int e = 1; e < NEXP; e++) if (lg[e] > lg[e0]) e0 = e;
        int e1 = (e0 == 0) ? 1 : 0;
#pragma unroll
        for (int e = 0; e < NEXP; e++) if (e != e0 && lg[e] > lg[e1]) e1 = e;
        float s0 = 1.f / (1.f + expf(lg[e1] - lg[e0]));
        tk_e[t] = make_int2(e0, e1);
        tk_s[t] = make_float2(s0, 1.f - s0);
    }
}

// ---------------- Routing: wave-aggregated list append + slot record ----------------
__global__ __launch_bounds__(256) void route_kernel(
    const int2* __restrict__ tk_e, const float2* __restrict__ tk_s,
    int* __restrict__ counts, int* __restrict__ ltok, float* __restrict__ lsc,
    int2* __restrict__ tk_pos, int T)
{
    int t    = blockIdx.x * 256 + threadIdx.x;
    int lane = threadIdx.x & 63;
    bool valid = t < T;
    int2   es = valid ? tk_e[t] : make_int2(-1, -1);
    float2 ss = valid ? tk_s[t] : make_float2(0.f, 0.f);
    int ppos[2] = {0, 0};

#pragma unroll
    for (int slot = 0; slot < 2; slot++) {
        int   e = slot ? es.y : es.x;
        float s = slot ? ss.y : ss.x;
#pragma unroll
        for (int ex = 0; ex < NEXP; ex++) {
            unsigned long long m = __ballot(e == ex);
            if (m == 0ull) continue;
            int leader = __ffsll((long long)m) - 1;
            int base = 0;
            if (lane == leader) base = atomicAdd(&counts[ex], __popcll(m));
            base = __shfl(base, leader, 64);
            if (e == ex) {
                int pos = base + __popcll(m & ((1ull << lane) - 1ull));
                ltok[(size_t)ex * T + pos] = t;
                lsc [(size_t)ex * T + pos] = s;
                ppos[slot] = pos | (ex << 16);
            }
        }
    }
    if (valid) tk_pos[t] = make_int2(ppos[0], ppos[1]);
}

// ------- Transpose-convert BOTH weights in ONE launch: [e][R][C] f32 -> [e][C][R] bf16
__global__ __launch_bounds__(256) void tcvt2_kernel(
    const float* __restrict__ W1, const float* __restrict__ W2,
    unsigned short* __restrict__ W1t, unsigned short* __restrict__ W2t)
{
    __shared__ unsigned short tile[64][72];
    int z = blockIdx.y;
    bool isw2 = z >= NEXP;
    int e = z & (NEXP - 1);
    int R = isw2 ? D_FF : D_MODEL;
    int C = isw2 ? D_MODEL : D_FF;
    const float* src = isw2 ? W2 : W1;
    unsigned short* dst = isw2 ? W2t : W1t;

    int nx  = C / 64;
    int lin = blockIdx.x;
    int r0 = (lin / nx) * 64, c0 = (lin % nx) * 64;

    const float* s = src + ((size_t)e * R + r0) * C + c0;
    unsigned short* d = dst + ((size_t)e * C + c0) * R + r0;
    int t = threadIdx.x;
#pragma unroll
    for (int i = 0; i < 4; i++) {
        int idx = t + 256 * i;
        int r = idx >> 4, c4 = (idx & 15) * 4;
        float4 v = *(const float4*)(s + (size_t)r * C + c4);
        tile[c4    ][r] = f2bf(v.x);
        tile[c4 + 1][r] = f2bf(v.y);
        tile[c4 + 2][r] = f2bf(v.z);
        tile[c4 + 3][r] = f2bf(v.w);
    }
    __syncthreads();
#pragma unroll
    for (int i = 0; i < 2; i++) {
        int idx = t + 256 * i;
        int c = idx >> 3, q = idx & 7;
        uint4 v = *(const uint4*)(&tile[c][q * 8]);
        *(uint4*)(d + (size_t)c * R + q * 8) = v;
    }
}

// ---------------- GEMM1: H = gelu(Xb @ W1t^T + b1) ----------------
// R12/R14 (unchanged): 128x128, 4 waves, 2 barriers/step, XCD swizzle.
__global__ __launch_bounds__(256, 4) void moe_gemm1(
    const unsigned short* __restrict__ Xb,
    const unsigned short* __restrict__ W1t, const float* __restrict__ b1,
    const int* __restrict__ counts, const int* __restrict__ ltok,
    unsigned short* __restrict__ Hg, int T)
{
    int nwg  = gridDim.x;
    int bid  = blockIdx.x;
    int work = (bid % NXCD) * (nwg / NXCD) + bid / NXCD;
    int perexp = nwg / NEXP;
    int e    = work / perexp;
    int rem  = work % perexp;
    int mbase = (rem >> 4) * 128;
    int fb    = (rem & 15) * 128;

    int n = counts[e];
    if (mbase >= n) return;
    int off = off_of(counts, e);

    __shared__ __align__(16) unsigned char SB[2][16384];
    __shared__ int toks_s[128];

    int tid = threadIdx.x, lane = tid & 63, w = tid >> 6;
    int wr = w & 1, wc = w >> 1;

    if (tid < 128) {
        int idx = mbase + tid; if (idx > n - 1) idx = n - 1;
        toks_s[tid] = ltok[(size_t)e * T + idx];
    }
    __syncthreads();

    const unsigned short* W1te = W1t + (size_t)e * D_FF * D_MODEL;
    int c = lane & 7, rsub = lane >> 3;

    const char* aptr[4]; const char* bptr[4]; int soff[4];
#pragma unroll
    for (int j = 0; j < 4; j++) {
        int r  = j * 32 + w * 8 + rsub;
        int sc = c ^ (r & 7);
        aptr[j] = (const char*)(Xb + (size_t)toks_s[r] * D_MODEL) + sc * 16;
        bptr[j] = (const char*)(W1te + (size_t)(fb + r) * D_MODEL) + sc * 16;
        soff[j] = (j * 32 + w * 8) * 128;
    }

    f32x4 acc[4][4];
#pragma unroll
    for (int i = 0; i < 4; i++)
#pragma unroll
        for (int j = 0; j < 4; j++) acc[i][j] = (f32x4){0.f, 0.f, 0.f, 0.f};

    for (int kc = 0; kc < D_MODEL; kc += 64) {
#pragma unroll
        for (int j = 0; j < 4; j++) gload_lds16(aptr[j] + kc * 2, SB[0] + soff[j]);
#pragma unroll
        for (int j = 0; j < 4; j++) gload_lds16(bptr[j] + kc * 2, SB[1] + soff[j]);
        __syncthreads();

#pragma unroll
        for (int ks = 0; ks < 2; ks++) {
            bf16x8 av[4], bv[4];
            int kbyte = ks * 64 + ((lane >> 4) * 16);
#pragma unroll
            for (int i = 0; i < 4; i++) {
                int row = wr * 64 + i * 16 + (lane & 15);
                av[i] = *(const bf16x8*)(SB[0] + row * 128 + (kbyte ^ ((row & 7) << 4)));
            }
#pragma unroll
            for (int j = 0; j < 4; j++) {
                int fr = wc * 64 + j * 16 + (lane & 15);
                bv[j] = *(const bf16x8*)(SB[1] + fr * 128 + (kbyte ^ ((fr & 7) << 4)));
            }
#pragma unroll
            for (int i = 0; i < 4; i++)
#pragma unroll
                for (int j = 0; j < 4; j++)
                    acc[i][j] = __builtin_amdgcn_mfma_f32_16x16x32_bf16(av[i], bv[j], acc[i][j], 0, 0, 0);
        }
        __syncthreads();
    }

    // epilogue: bias+GELU -> swizzled LDS (bf16) -> coalesced uint4 stores
    char* Eb = (char*)&SB[0][0];
    const float* b1e = b1 + (size_t)e * D_FF;
#pragma unroll
    for (int j = 0; j < 4; j++) {
        int col = wc * 64 + j * 16 + (lane & 15);
        float b1v = b1e[fb + col];
#pragma unroll
        for (int i = 0; i < 4; i++) {
#pragma unroll
            for (int r = 0; r < 4; r++) {
                int row = wr * 64 + i * 16 + (lane >> 4) * 4 + r;
                float v = gelu_exact(acc[i][j][r] + b1v);
                *(unsigned short*)(Eb + row * 256 + ((col * 2) ^ ((row & 7) << 4))) = f2bf(v);
            }
        }
    }
    __syncthreads();
#pragma unroll
    for (int k = 0; k < 8; k++) {
        int idx = tid + 256 * k;
        int row = idx >> 4, ch = idx & 15;
        if (mbase + row < n) {
            uint4 v = *(const uint4*)(Eb + row * 256 + ((ch * 16) ^ ((row & 7) << 4)));
            *(uint4*)(Hg + (size_t)(off + mbase + row) * D_FF + fb + ch * 8) = v;
        }
    }
}

// ---------------- GEMM2 (atomic-free): Og16[kb][slot][d] = bf16(s*(H@W2t^T + b2)) ----
// R12 K-loop; bf16 output routed through swizzled LDS -> coalesced stores.
__global__ __launch_bounds__(256, 4) void moe_gemm2_og(
    const unsigned short* __restrict__ Hg,
    const unsigned short* __restrict__ W2t, const float* __restrict__ b2,
    const int* __restrict__ counts, const int* __restrict__ ltok,
    const float* __restrict__ lsc,
    unsigned short* __restrict__ Og, int T)
{
    int nwg  = gridDim.x;
    int bid  = blockIdx.x;
    int work = (bid % NXCD) * (nwg / NXCD) + bid / NXCD;
    int perexp = nwg / NEXP;
    int e    = work / perexp;
    int rem  = work % perexp;
    int mbase = (rem >> 3) * 128;
    int z    = rem & 7;
    int nb   = z & 3, kb = z >> 2;
    int db   = nb * 128;

    int n = counts[e];
    if (mbase >= n) return;
    int off = off_of(counts, e);

    __shared__ __align__(16) unsigned char SB[2][16384];   // A, B; epilogue reuses 32KB
    __shared__ float scs_s[128];

    int tid = threadIdx.x, lane = tid & 63, w = tid >> 6;
    int wr = w & 1, wc = w >> 1;

    if (tid < 128) {
        int idx = mbase + tid; if (idx > n - 1) idx = n - 1;
        scs_s[tid] = lsc[(size_t)e * T + idx];
    }
    __syncthreads();

    const unsigned short* W2te = W2t + (size_t)e * D_MODEL * D_FF;
    int c = lane & 7, rsub = lane >> 3;

    const char* aptr[4]; const char* bptr[4]; int soff[4];
#pragma unroll
    for (int j = 0; j < 4; j++) {
        int r = j * 32 + w * 8 + rsub;
        int srow = mbase + r; if (srow > n - 1) srow = n - 1;
        int sc = c ^ (r & 7);
        aptr[j] = (const char*)(Hg + (size_t)(off + srow) * D_FF) + sc * 16;
        bptr[j] = (const char*)(W2te + (size_t)(db + r) * D_FF) + sc * 16;
        soff[j] = (j * 32 + w * 8) * 128;
    }

    f32x4 acc[4][4];
#pragma unroll
    for (int i = 0; i < 4; i++)
#pragma unroll
        for (int j = 0; j < 4; j++) acc[i][j] = (f32x4){0.f, 0.f, 0.f, 0.f};

    int kbase = kb * 1024;
    for (int kc = 0; kc < 1024; kc += 64) {
        int kabs = kbase + kc;
#pragma unroll
        for (int j = 0; j < 4; j++) gload_lds16(aptr[j] + kabs * 2, SB[0] + soff[j]);
#pragma unroll
        for (int j = 0; j < 4; j++) gload_lds16(bptr[j] + kabs * 2, SB[1] + soff[j]);
        __syncthreads();

#pragma unroll
        for (int ks = 0; ks < 2; ks++) {
            bf16x8 av[4], bv[4];
            int kbyte = ks * 64 + ((lane >> 4) * 16);
#pragma unroll
            for (int i = 0; i < 4; i++) {
                int row = wr * 64 + i * 16 + (lane & 15);
                av[i] = *(const bf16x8*)(SB[0] + row * 128 + (kbyte ^ ((row & 7) << 4)));
            }
#pragma unroll
            for (int j = 0; j < 4; j++) {
                int dr = wc * 64 + j * 16 + (lane & 15);
                bv[j] = *(const bf16x8*)(SB[1] + dr * 128 + (kbyte ^ ((dr & 7) << 4)));
            }
#pragma unroll
            for (int i = 0; i < 4; i++)
#pragma unroll
                for (int j = 0; j < 4; j++)
                    acc[i][j] = __builtin_amdgcn_mfma_f32_16x16x32_bf16(av[i], bv[j], acc[i][j], 0, 0, 0);
        }
        __syncthreads();
    }

    // epilogue: s*(acc+b2) -> bf16 swizzled LDS -> coalesced 256B-row stores
    char* Eb = (char*)&SB[0][0];
#pragma unroll
    for (int j = 0; j < 4; j++) {
        int col = wc * 64 + j * 16 + (lane & 15);
        float b2v = (kb == 0) ? b2[(size_t)e * D_MODEL + db + col] : 0.f;
#pragma unroll
        for (int i = 0; i < 4; i++) {
#pragma unroll
            for (int r = 0; r < 4; r++) {
                int row = wr * 64 + i * 16 + (lane >> 4) * 4 + r;
                float v = scs_s[row] * (acc[i][j][r] + b2v);
                *(unsigned short*)(Eb + row * 256 + ((col * 2) ^ ((row & 7) << 4))) = f2bf(v);
            }
        }
    }
    __syncthreads();
    unsigned short* Ogk = Og + (size_t)kb * (2 * T) * D_MODEL;
#pragma unroll
    for (int k = 0; k < 8; k++) {
        int idx = tid + 256 * k;
        int row = idx >> 4, ch = idx & 15;
        if (mbase + row < n) {
            uint4 v = *(const uint4*)(Eb + row * 256 + ((ch * 16) ^ ((row & 7) << 4)));
            *(uint4*)(Ogk + (size_t)(off + mbase + row) * D_MODEL + db + ch * 8) = v;
        }
    }
}

// ---------------- Combine: out[t] = sum of 4 bf16 partial rows ----------------
__global__ __launch_bounds__(256) void combine_kernel(
    const unsigned short* __restrict__ Og, const int* __restrict__ counts,
    const int2* __restrict__ tk_pos, float* __restrict__ out, int T)
{
    int w = threadIdx.x >> 6, lane = threadIdx.x & 63;
    int t = blockIdx.x * 4 + w;
    if (t >= T) return;
    int2 p = tk_pos[t];
    int eA = p.x >> 16, eB = p.y >> 16;
    int offA = 0, offB = 0;
#pragma unroll
    for (int i = 0; i < NEXP; i++) {
        int cv = counts[i];
        if (i < eA) offA += cv;
        if (i < eB) offB += cv;
    }
    int sA = offA + (p.x & 0xffff);
    int sB = offB + (p.y & 0xffff);
    size_t S = (size_t)(2 * T) * D_MODEL;
    int base = lane * 8;
    const unsigned short* r0 = Og + (size_t)sA * D_MODEL + base;
    const unsigned short* r1 = Og + S + (size_t)sA * D_MODEL + base;
    const unsigned short* r2 = Og + (size_t)sB * D_MODEL + base;
    const unsigned short* r3 = Og + S + (size_t)sB * D_MODEL + base;

    ushort4 a0 = *(const ushort4*)(r0), a1 = *(const ushort4*)(r0 + 4);
    ushort4 b0 = *(const ushort4*)(r1), b1 = *(const ushort4*)(r1 + 4);
    ushort4 c0 = *(const ushort4*)(r2), c1 = *(const ushort4*)(r2 + 4);
    ushort4 d0 = *(const ushort4*)(r3), d1 = *(const ushort4*)(r3 + 4);

    float4 o0, o1;
    o0.x = bf2f(a0.x) + bf2f(b0.x) + bf2f(c0.x) + bf2f(d0.x);
    o0.y = bf2f(a0.y) + bf2f(b0.y) + bf2f(c0.y) + bf2f(d0.y);
    o0.z = bf2f(a0.z) + bf2f(b0.z) + bf2f(c0.z) + bf2f(d0.z);
    o0.w = bf2f(a0.w) + bf2f(b0.w) + bf2f(c0.w) + bf2f(d0.w);
    o1.x = bf2f(a1.x) + bf2f(b1.x) + bf2f(c1.x) + bf2f(d1.x);
    o1.y = bf2f(a1.y) + bf2f(b1.y) + bf2f(c1.y) + bf2f(d1.y);
    o1.z = bf2f(a1.z) + bf2f(b1.z) + bf2f(c1.z) + bf2f(d1.z);
    o1.w = bf2f(a1.w) + bf2f(b1.w) + bf2f(c1.w) + bf2f(d1.w);

    float* orow = out + (size_t)t * D_MODEL + base;
    *(float4*)(orow)     = o0;
    *(float4*)(orow + 4) = o1;
}

// ---------------- GEMM2 (atomic fallback, small-ws path) ----------------
__global__ __launch_bounds__(256, 4) void moe_gemm2(
    const unsigned short* __restrict__ Hg,
    const unsigned short* __restrict__ W2t, const float* __restrict__ b2,
    const int* __restrict__ counts, const int* __restrict__ ltok,
    const float* __restrict__ lsc,
    float* __restrict__ out, int T)
{
    int e = blockIdx.x;
    int n = counts[e];
    int mbase = blockIdx.y * 128;
    if (mbase >= n) return;
    int nb = blockIdx.z & 3, kb = blockIdx.z >> 2;
    int db = nb * 128;
    int off = off_of(counts, e);

    __shared__ __align__(16) unsigned char HsB[128 * 128];
    __shared__ __align__(16) unsigned char WsB[128 * 128];
    __shared__ int   toks_s[128];
    __shared__ float scs_s[128];

    int tid = threadIdx.x, lane = tid & 63, w = tid >> 6;
    int wr = w & 1, wc = w >> 1;

    if (tid < 128) {
        int idx = mbase + tid; if (idx > n - 1) idx = n - 1;
        toks_s[tid] = ltok[(size_t)e * T + idx];
        scs_s [tid] = lsc [(size_t)e * T + idx];
    }
    __syncthreads();

    const unsigned short* W2te = W2t + (size_t)e * D_MODEL * D_FF;
    int c = lane & 7, rsub = lane >> 3;

    const char* aptr[4]; const char* bptr[4]; int soff[4];
#pragma unroll
    for (int j = 0; j < 4; j++) {
        int r = j * 32 + w * 8 + rsub;
        int srow = mbase + r; if (srow > n - 1) srow = n - 1;
        int sc = c ^ (r & 7);
        aptr[j] = (const char*)(Hg + (size_t)(off + srow) * D_FF) + sc * 16;
        bptr[j] = (const char*)(W2te + (size_t)(db + r) * D_FF) + sc * 16;
        soff[j] = (j * 32 + w * 8) * 128;
    }

    f32x4 acc[4][4];
#pragma unroll
    for (int i = 0; i < 4; i++)
#pragma unroll
        for (int j = 0; j < 4; j++) acc[i][j] = (f32x4){0.f, 0.f, 0.f, 0.f};

    int kbase = kb * 1024;
    for (int kc = 0; kc < 1024; kc += 64) {
        int kabs = kbase + kc;
#pragma unroll
        for (int j = 0; j < 4; j++) gload_lds16(aptr[j] + kabs * 2, HsB + soff[j]);
#pragma unroll
        for (int j = 0; j < 4; j++) gload_lds16(bptr[j] + kabs * 2, WsB + soff[j]);
        __syncthreads();

#pragma unroll
        for (int ks = 0; ks < 2; ks++) {
            bf16x8 av[4], bv[4];
            int kbyte = ks * 64 + ((lane >> 4) * 16);
#pragma unroll
            for (int i = 0; i < 4; i++) {
                int row = wr * 64 + i * 16 + (lane & 15);
                av[i] = *(const bf16x8*)(HsB + row * 128 + (kbyte ^ ((row & 7) << 4)));
            }
#pragma unroll
            for (int j = 0; j < 4; j++) {
                int dr = wc * 64 + j * 16 + (lane & 15);
                bv[j] = *(const bf16x8*)(WsB + dr * 128 + (kbyte ^ ((dr & 7) << 4)));
            }
#pragma unroll
            for (int i = 0; i < 4; i++)
#pragma unroll
                for (int j = 0; j < 4; j++)
                    acc[i][j] = __builtin_amdgcn_mfma_f32_16x16x32_bf16(av[i], bv[j], acc[i][j], 0, 0, 0);
        }
        __syncthreads();
    }

#pragma unroll
    for (int j = 0; j < 4; j++) {
        int dg = db + wc * 64 + j * 16 + (lane & 15);
        float b2v = (kb == 0) ? b2[(size_t)e * D_MODEL + dg] : 0.f;
#pragma unroll
        for (int i = 0; i < 4; i++) {
#pragma unroll
            for (int r = 0; r < 4; r++) {
                int rowm = wr * 64 + i * 16 + (lane >> 4) * 4 + r;
                if (mbase + rowm < n) {
                    float s = scs_s[rowm];
                    int tok = toks_s[rowm];
                    atomicAdd(out + (size_t)tok * D_MODEL + dg, s * (acc[i][j][r] + b2v));
                }
            }
        }
    }
}

// ---------------- Fallback: register-staging GEMMs (fp32 weights, small ws) ----------------
__global__ __launch_bounds__(512, 2) void moe_gemm1_rs(
    const float* __restrict__ x,
    const float* __restrict__ W1, const float* __restrict__ b1,
    const int* __restrict__ counts, const int* __restrict__ ltok,
    unsigned short* __restrict__ Hg, int T)
{
    int e = blockIdx.x;
    int n = counts[e];
    int mbase = blockIdx.y * 128;
    if (mbase >= n) return;
    int fb = blockIdx.z * 256;
    int off = off_of(counts, e);

    __shared__ __align__(16) unsigned char XsB[128 * 128];
    __shared__ __align__(16) unsigned char WtB[256 * 128];
    __shared__ int toks_s[128];

    int tid  = threadIdx.x;
    int lane = tid & 63;
    int w    = tid >> 6;
    int wr   = w & 1, wc = w >> 1;

    if (tid < 128) {
        int idx = mbase + tid; if (idx > n - 1) idx = n - 1;
        toks_s[tid] = ltok[(size_t)e * T + idx];
    }
    __syncthreads();

    const float* W1e = W1 + (size_t)e * D_MODEL * D_FF;

    f32x4 acc[4][4];
#pragma unroll
    for (int i = 0; i < 4; i++)
#pragma unroll
        for (int j = 0; j < 4; j++) acc[i][j] = (f32x4){0.f, 0.f, 0.f, 0.f};

    int fcol = tid & 255, khalf = tid >> 8;
    const float* w1col = W1e + fb + fcol;

    for (int kc = 0; kc < D_MODEL; kc += 64) {
#pragma unroll
        for (int i = 0; i < 4; i++) {
            int idx = tid + 512 * i;
            int r = idx >> 4, c4 = idx & 15;
            const float4 v = *(const float4*)(x + (size_t)toks_s[r] * D_MODEL + kc + c4 * 4);
            *(uint2*)(XsB + r * 128 + ((c4 * 8) ^ ((r & 7) << 4))) =
                make_uint2(pk(v.x, v.y), pk(v.z, v.w));
        }
#pragma unroll
        for (int j = 0; j < 8; j++) {
            int q  = khalf * 8 + j;
            int k0 = kc + q * 4;
            float a0 = w1col[(size_t)(k0    ) * D_FF];
            float a1 = w1col[(size_t)(k0 + 1) * D_FF];
            float a2 = w1col[(size_t)(k0 + 2) * D_FF];
            float a3 = w1col[(size_t)(k0 + 3) * D_FF];
            *(uint2*)(WtB + fcol * 128 + ((q * 8) ^ ((fcol & 7) << 4))) =
                make_uint2(pk(a0, a1), pk(a2, a3));
        }
        __syncthreads();

#pragma unroll
        for (int ks = 0; ks < 2; ks++) {
            bf16x8 av[4], bv[4];
            int kbyte = ks * 64 + ((lane >> 4) * 16);
#pragma unroll
            for (int i = 0; i < 4; i++) {
                int row = wr * 64 + i * 16 + (lane & 15);
                av[i] = *(const bf16x8*)(XsB + row * 128 + (kbyte ^ ((row & 7) << 4)));
            }
#pragma unroll
            for (int j = 0; j < 4; j++) {
                int fr = wc * 64 + j * 16 + (lane & 15);
                bv[j] = *(const bf16x8*)(WtB + fr * 128 + (kbyte ^ ((fr & 7) << 4)));
            }
#pragma unroll
            for (int i = 0; i < 4; i++)
#pragma unroll
                for (int j = 0; j < 4; j++)
                    acc[i][j] = __builtin_amdgcn_mfma_f32_16x16x32_bf16(av[i], bv[j], acc[i][j], 0, 0, 0);
        }
        __syncthreads();
    }

    const float* b1e = b1 + (size_t)e * D_FF;
#pragma unroll
    for (int j = 0; j < 4; j++) {
        int fg = fb + wc * 64 + j * 16 + (lane & 15);
        float b1v = b1e[fg];
#pragma unroll
        for (int i = 0; i < 4; i++) {
#pragma unroll
            for (int r = 0; r < 4; r++) {
                int rowm = wr * 64 + i * 16 + (lane >> 4) * 4 + r;
                if (mbase + rowm < n) {
                    float v = gelu_exact(acc[i][j][r] + b1v);
                    Hg[(size_t)(off + mbase + rowm) * D_FF + fg] = f2bf(v);
                }
            }
        }
    }
}

__global__ __launch_bounds__(512, 2) void moe_gemm2_rs(
    const unsigned short* __restrict__ Hg,
    const float* __restrict__ W2, const float* __restrict__ b2,
    const int* __restrict__ counts, const int* __restrict__ ltok,
    const float* __restrict__ lsc,
    float* __restrict__ out, int T)
{
    int e = blockIdx.x;
    int n = counts[e];
    int mbase = blockIdx.y * 128;
    if (mbase >= n) return;
    int nb = blockIdx.z & 1, kb = blockIdx.z >> 1;
    int db = nb * 256;
    int off = off_of(counts, e);

    __shared__ __align__(16) unsigned char HsB[128 * 128];
    __shared__ __align__(16) unsigned char WtB[256 * 128];
    __shared__ int   toks_s[128];
    __shared__ float scs_s[128];

    int tid  = threadIdx.x;
    int lane = tid & 63;
    int w    = tid >> 6;
    int wr   = w & 1, wc = w >> 1;

    if (tid < 128) {
        int idx = mbase + tid; if (idx > n - 1) idx = n - 1;
        toks_s[tid] = ltok[(size_t)e * T + idx];
        scs_s [tid] = lsc [(size_t)e * T + idx];
    }
    __syncthreads();

    const float* W2e = W2 + (size_t)e * D_FF * D_MODEL;

    f32x4 acc[4][4];
#pragma unroll
    for (int i = 0; i < 4; i++)
#pragma unroll
        for (int j = 0; j < 4; j++) acc[i][j] = (f32x4){0.f, 0.f, 0.f, 0.f};

    int dcol = tid & 255, khalf = tid >> 8;
    const float* w2col = W2e + db + dcol;

    for (int kc = 0; kc < 1024; kc += 64) {
        int kabs = kb * 1024 + kc;
#pragma unroll
        for (int i = 0; i < 2; i++) {
            int idx = tid + 512 * i;
            int r = idx >> 3, c16 = idx & 7;
            int srow = mbase + r; if (srow > n - 1) srow = n - 1;
            const uint4 v = *(const uint4*)(Hg + (size_t)(off + srow) * D_FF + kabs + c16 * 8);
            *(uint4*)(HsB + r * 128 + ((c16 * 16) ^ ((r & 7) << 4))) = v;
        }
#pragma unroll
        for (int j = 0; j < 8; j++) {
            int q  = khalf * 8 + j;
            int k0 = kabs + q * 4;
            float a0 = w2col[(size_t)(k0    ) * D_MODEL];
            float a1 = w2col[(size_t)(k0 + 1) * D_MODEL];
            float a2 = w2col[(size_t)(k0 + 2) * D_MODEL];
            float a3 = w2col[(size_t)(k0 + 3) * D_MODEL];
            *(uint2*)(WtB + dcol * 128 + ((q * 8) ^ ((dcol & 7) << 4))) =
                make_uint2(pk(a0, a1), pk(a2, a3));
        }
        __syncthreads();

#pragma unroll
        for (int ks = 0; ks < 2; ks++) {
            bf16x8 av[4], bv[4];
            int kbyte = ks * 64 + ((lane >> 4) * 16);
#pragma unroll
            for (int i = 0; i < 4; i++) {
                int row = wr * 64 + i * 16 + (lane & 15);
                av[i] = *(const bf16x8*)(HsB + row * 128 + (kbyte ^ ((row & 7) << 4)));
            }
#pragma unroll
            for (int j = 0; j < 4; j++) {
                int dr = wc * 64 + j * 16 + (lane & 15);
                bv[j] = *(const bf16x8*)(WtB + dr * 128 + (kbyte ^ ((dr & 7) << 4)));
            }
#pragma unroll
            for (int i = 0; i < 4; i++)
#pragma unroll
                for (int j = 0; j < 4; j++)
                    acc[i][j] = __builtin_amdgcn_mfma_f32_16x16x32_bf16(av[i], bv[j], acc[i][j], 0, 0, 0);
        }
        __syncthreads();
    }

#pragma unroll
    for (int j = 0; j < 4; j++) {
        int dg = db + wc * 64 + j * 16 + (lane & 15);
        float b2v = (kb == 0) ? b2[(size_t)e * D_MODEL + dg] : 0.f;
#pragma unroll
        for (int i = 0; i < 4; i++) {
#pragma unroll
            for (int r = 0; r < 4; r++) {
                int rowm = wr * 64 + i * 16 + (lane >> 4) * 4 + r;
                if (mbase + rowm < n) {
                    float s = scs_s[rowm];
                    int tok = toks_s[rowm];
                    atomicAdd(out + (size_t)tok * D_MODEL + dg, s * (acc[i][j][r] + b2v));
                }
            }
        }
    }
}

extern "C" void kernel_launch(void* const* d_in, const int* in_sizes, int n_in,
                              void* d_out, int out_size, void* d_ws, size_t ws_size,
                              hipStream_t stream)
{
    const float* x  = (const float*)d_in[0];
    const float* Wg = (const float*)d_in[1];
    const float* bg = (const float*)d_in[2];
    const float* W1 = (const float*)d_in[3];
    const float* b1 = (const float*)d_in[4];
    const float* W2 = (const float*)d_in[5];
    const float* b2 = (const float*)d_in[6];
    float* out = (float*)d_out;
    int T = in_sizes[0] / D_MODEL;  // 4096

    // base region (< 512 KB)
    int*    counts = (int*)d_ws;
    int*    ltok   = (int*)((char*)d_ws + 256);
    float*  lsc    = (float*)((char*)d_ws + 256 + (size_t)NEXP * T * sizeof(int));
    int2*   tk_e   = (int2*)((char*)d_ws + 256 + (size_t)2 * NEXP * T * sizeof(int));
    float2* tk_s   = (float2*)((char*)tk_e + (size_t)T * sizeof(int2));
    int2*   tk_pos = (int2*)((char*)tk_s + (size_t)T * sizeof(float2));

    const size_t Hoff   = 512 * 1024;
    const size_t Hbytes = (size_t)2 * T * D_FF * sizeof(unsigned short);
    const size_t Xoff   = Hoff + Hbytes;
    const size_t Xbytes = (size_t)T * D_MODEL * sizeof(unsigned short);
    const size_t W1off  = Xoff + Xbytes;
    const size_t Wbytes = (size_t)NEXP * D_MODEL * D_FF * sizeof(unsigned short);
    const size_t W2off  = W1off + Wbytes;
    const size_t Ogoff  = W2off + Wbytes;
    const size_t Ogbytes = (size_t)2 * (2 * T) * D_MODEL * sizeof(unsigned short);
    const size_t need_og   = Ogoff + Ogbytes + 4096;
    const size_t need_full = W2off + Wbytes + 4096;
    const size_t need_r2   = Hoff + Hbytes + 4096;

    bool og   = ws_size >= need_og;
    bool full = ws_size >= need_full;
    unsigned short* Xb = full ? (unsigned short*)((char*)d_ws + Xoff) : nullptr;

    hipMemsetAsync(d_ws, 0, 256, stream);
    if (!og)
        hipMemsetAsync(d_out, 0, (size_t)out_size * sizeof(float), stream);

    gate_kernel<<<dim3((T + 3) / 4), dim3(256), 0, stream>>>(
        x, Wg, bg, tk_e, tk_s, Xb, T);
    route_kernel<<<dim3((T + 255) / 256), dim3(256), 0, stream>>>(
        tk_e, tk_s, counts, ltok, lsc, tk_pos, T);

    if (full) {
        unsigned short* Hg  = (unsigned short*)((char*)d_ws + Hoff);
        unsigned short* W1t = (unsigned short*)((char*)d_ws + W1off);
        unsigned short* W2t = (unsigned short*)((char*)d_ws + W2off);

        tcvt2_kernel<<<dim3(256, 2 * NEXP), dim3(256), 0, stream>>>(W1, W2, W1t, W2t);

        int ytiles = (T + 127) / 128;   // 32
        int g1 = NEXP * ytiles * (D_FF / 128);   // 4096, %8==0
        moe_gemm1<<<dim3(g1), dim3(256), 0, stream>>>(
            Xb, W1t, b1, counts, ltok, Hg, T);

        if (og) {
            unsigned short* Og = (unsigned short*)((char*)d_ws + Ogoff);
            int g2 = NEXP * ytiles * 8;          // 2048, %8==0
            moe_gemm2_og<<<dim3(g2), dim3(256), 0, stream>>>(
                Hg, W2t, b2, counts, ltok, lsc, Og, T);
            combine_kernel<<<dim3((T + 3) / 4), dim3(256), 0, stream>>>(
                Og, counts, tk_pos, out, T);
        } else {
            moe_gemm2<<<dim3(NEXP, ytiles, 8), dim3(256), 0, stream>>>(
                Hg, W2t, b2, counts, ltok, lsc, out, T);
        }
    } else if (ws_size >= need_r2) {
        unsigned short* Hg = (unsigned short*)((char*)d_ws + Hoff);
        moe_gemm1_rs<<<dim3(NEXP, (T + 127) / 128, D_FF / 256), dim3(512), 0, stream>>>(
            x, W1, b1, counts, ltok, Hg, T);
        moe_gemm2_rs<<<dim3(NEXP, (T + 127) / 128, 4), dim3(512), 0, stream>>>(
            Hg, W2, b2, counts, ltok, lsc, out, T);
    }
}